// Round 1
// baseline (447.332 us; speedup 1.0000x reference)
//
#include <hip/hip_runtime.h>

typedef _Float16 f16;
typedef f16 f16x8 __attribute__((ext_vector_type(8)));
typedef f16 f16x4 __attribute__((ext_vector_type(4)));
typedef short s16x8 __attribute__((ext_vector_type(8)));
typedef short s16x4 __attribute__((ext_vector_type(4)));
typedef float f32x4 __attribute__((ext_vector_type(4)));

#define MFMA16(a,b,c)  __builtin_amdgcn_mfma_f32_16x16x32_f16(a,b,c,0,0,0)
#define MFMAB16(a,b,c) __builtin_amdgcn_mfma_f32_16x16x32_bf16(a,b,c,0,0,0)

static constexpr int Bn = 8, Qn = 2048, Kn = 2048, Hn = 512;
static constexpr int Mn = Bn * Qn;           // 16384 flat rows

__device__ __forceinline__ short bf16r(float x) {
    unsigned u = __builtin_bit_cast(unsigned, x);
    u += 0x7fffu + ((u >> 16) & 1u);
    return (short)(u >> 16);
}

// ---------------------------------------------------------------------------
// prep_w: build transposed, split weight matrices.
//   Wqt/Wkt: W^T * 512 split into fp16 hi + fp16 lo*2^11  (keeps lo normal)
//   Wvt/Wot: W^T in bf16
// ---------------------------------------------------------------------------
__global__ __launch_bounds__(256) void prep_w(
    const float* __restrict__ Wq, const float* __restrict__ Wk,
    const float* __restrict__ Wv, const float* __restrict__ Wo,
    f16* __restrict__ Wqth, f16* __restrict__ Wqtl,
    f16* __restrict__ Wkth, f16* __restrict__ Wktl,
    short* __restrict__ Wvt, short* __restrict__ Wot)
{
    int e = blockIdx.x * 256 + threadIdx.x;     // 512*512
    int k = e >> 9, n = e & 511;
    int s = k * 512 + n, d = n * 512 + k;
    float wq = Wq[s] * 512.0f;
    f16 h = (f16)wq;
    Wqth[d] = h; Wqtl[d] = (f16)((wq - (float)h) * 2048.0f);
    float wk = Wk[s] * 512.0f;
    h = (f16)wk;
    Wkth[d] = h; Wktl[d] = (f16)((wk - (float)h) * 2048.0f);
    Wvt[d] = bf16r(Wv[s]);
    Wot[d] = bf16r(Wo[s]);
}

// ---------------------------------------------------------------------------
// proj_split: P = (A @ Wt^T)/512 + bias, A f32, Wt fp16 split pair.
// 3-product fp16x2 GEMM -> writes P as fp16 hi/lo pair (lo scaled 2^11).
// Tile 128x128, BK=32, 4 waves (2x2), 16x16x32 MFMA.
// ---------------------------------------------------------------------------
__global__ __launch_bounds__(256) void proj_split(
    const float* __restrict__ A,
    const f16* __restrict__ Bth, const f16* __restrict__ Btl,
    const float* __restrict__ bias,
    f16* __restrict__ Ph, f16* __restrict__ Pl)
{
    __shared__ __align__(16) f16 Ah[4096], Al[4096], Bh[4096], Bl[4096];
    const int tid = threadIdx.x, lane = tid & 63, wid = tid >> 6;
    const int wr = wid >> 1, wc = wid & 1, l15 = lane & 15, lg = lane >> 4;
    const int m0 = blockIdx.x * 128, n0 = blockIdx.y * 128;
    f32x4 a0[4][4] = {}, a1[4][4] = {};
    const int ar0 = tid >> 3, ac0 = (tid & 7) * 4;   // A stage: 32 rows/pass
    const int br0 = tid >> 2, bc0 = (tid & 3) * 8;   // B stage: 64 rows/pass

    #pragma unroll 1
    for (int ks = 0; ks < 16; ++ks) {
        const int k0 = ks * 32;
        __syncthreads();
        #pragma unroll
        for (int rr = 0; rr < 4; ++rr) {
            int row = ar0 + rr * 32;
            f32x4 v = *(const f32x4*)(A + (size_t)(m0 + row) * Hn + k0 + ac0);
            f16x4 oh, ol;
            #pragma unroll
            for (int j = 0; j < 4; ++j) {
                f16 hh = (f16)v[j];
                oh[j] = hh;
                ol[j] = (f16)((v[j] - (float)hh) * 2048.0f);
            }
            int off = row * 32 + (((ac0 >> 3) ^ (row & 3)) << 3) + (ac0 & 7);
            *(f16x4*)&Ah[off] = oh;
            *(f16x4*)&Al[off] = ol;
        }
        #pragma unroll
        for (int rr = 0; rr < 2; ++rr) {
            int row = br0 + rr * 64;
            size_t g = (size_t)(n0 + row) * Hn + k0 + bc0;
            int off = row * 32 + (((bc0 >> 3) ^ (row & 3)) << 3);
            *(f16x8*)&Bh[off] = *(const f16x8*)(Bth + g);
            *(f16x8*)&Bl[off] = *(const f16x8*)(Btl + g);
        }
        __syncthreads();
        f16x8 fbh[4], fbl[4];
        #pragma unroll
        for (int fj = 0; fj < 4; ++fj) {
            int row = wc * 64 + fj * 16 + l15;
            int off = row * 32 + ((lg ^ (row & 3)) << 3);
            fbh[fj] = *(f16x8*)&Bh[off];
            fbl[fj] = *(f16x8*)&Bl[off];
        }
        #pragma unroll
        for (int fi = 0; fi < 4; ++fi) {
            int row = wr * 64 + fi * 16 + l15;
            int off = row * 32 + ((lg ^ (row & 3)) << 3);
            f16x8 fah = *(f16x8*)&Ah[off];
            f16x8 fal = *(f16x8*)&Al[off];
            #pragma unroll
            for (int fj = 0; fj < 4; ++fj) {
                a0[fi][fj] = MFMA16(fah, fbh[fj], a0[fi][fj]);
                a1[fi][fj] = MFMA16(fah, fbl[fj], a1[fi][fj]);
                a1[fi][fj] = MFMA16(fal, fbh[fj], a1[fi][fj]);
            }
        }
    }
    #pragma unroll
    for (int fi = 0; fi < 4; ++fi)
    #pragma unroll
    for (int fj = 0; fj < 4; ++fj)
    #pragma unroll
    for (int j = 0; j < 4; ++j) {
        int m = m0 + wr * 64 + fi * 16 + lg * 4 + j;
        int n = n0 + wc * 64 + fj * 16 + l15;
        float v = (a0[fi][fj][j] + a1[fi][fj][j] * (1.0f / 2048.0f)) * (1.0f / 512.0f) + bias[n];
        f16 h = (f16)v;
        Ph[(size_t)m * Hn + n] = h;
        Pl[(size_t)m * Hn + n] = (f16)((v - (float)h) * 2048.0f);
    }
}

// ---------------------------------------------------------------------------
// gemm_bf: single-product bf16 GEMM_BT, C = A @ Bt^T + bias.
// A_F32: A is f32, converted to bf16 on the fly (value projection).
// OUT_F32: write f32 (final res), else bf16.
// ---------------------------------------------------------------------------
template<int A_F32, int OUT_F32>
__global__ __launch_bounds__(256) void gemm_bf(
    const void* __restrict__ Asrc, const short* __restrict__ Bt,
    const float* __restrict__ bias, void* __restrict__ Out)
{
    __shared__ __align__(16) short As[4096], Bs[4096];
    const int tid = threadIdx.x, lane = tid & 63, wid = tid >> 6;
    const int wr = wid >> 1, wc = wid & 1, l15 = lane & 15, lg = lane >> 4;
    const int m0 = blockIdx.x * 128, n0 = blockIdx.y * 128;
    f32x4 acc[4][4] = {};
    const int ar0 = tid >> 3, ac0 = (tid & 7) * 4;
    const int br0 = tid >> 2, bc0 = (tid & 3) * 8;

    #pragma unroll 1
    for (int ks = 0; ks < 16; ++ks) {
        const int k0 = ks * 32;
        __syncthreads();
        if (A_F32) {
            #pragma unroll
            for (int rr = 0; rr < 4; ++rr) {
                int row = ar0 + rr * 32;
                f32x4 v = *(const f32x4*)((const float*)Asrc + (size_t)(m0 + row) * Hn + k0 + ac0);
                s16x4 o;
                #pragma unroll
                for (int j = 0; j < 4; ++j) o[j] = bf16r(v[j]);
                int off = row * 32 + (((ac0 >> 3) ^ (row & 3)) << 3) + (ac0 & 7);
                *(s16x4*)&As[off] = o;
            }
        } else {
            #pragma unroll
            for (int rr = 0; rr < 2; ++rr) {
                int row = br0 + rr * 64;
                int off = row * 32 + (((bc0 >> 3) ^ (row & 3)) << 3);
                *(s16x8*)&As[off] = *(const s16x8*)((const short*)Asrc + (size_t)(m0 + row) * Hn + k0 + bc0);
            }
        }
        #pragma unroll
        for (int rr = 0; rr < 2; ++rr) {
            int row = br0 + rr * 64;
            int off = row * 32 + (((bc0 >> 3) ^ (row & 3)) << 3);
            *(s16x8*)&Bs[off] = *(const s16x8*)(Bt + (size_t)(n0 + row) * Hn + k0 + bc0);
        }
        __syncthreads();
        s16x8 fb[4];
        #pragma unroll
        for (int fj = 0; fj < 4; ++fj) {
            int row = wc * 64 + fj * 16 + l15;
            fb[fj] = *(s16x8*)&Bs[row * 32 + ((lg ^ (row & 3)) << 3)];
        }
        #pragma unroll
        for (int fi = 0; fi < 4; ++fi) {
            int row = wr * 64 + fi * 16 + l15;
            s16x8 fa = *(s16x8*)&As[row * 32 + ((lg ^ (row & 3)) << 3)];
            #pragma unroll
            for (int fj = 0; fj < 4; ++fj)
                acc[fi][fj] = MFMAB16(fa, fb[fj], acc[fi][fj]);
        }
    }
    #pragma unroll
    for (int fi = 0; fi < 4; ++fi)
    #pragma unroll
    for (int fj = 0; fj < 4; ++fj)
    #pragma unroll
    for (int j = 0; j < 4; ++j) {
        int m = m0 + wr * 64 + fi * 16 + lg * 4 + j;
        int n = n0 + wc * 64 + fj * 16 + l15;
        float v = acc[fi][fj][j] + bias[n];
        if (OUT_F32) ((float*)Out)[(size_t)m * Hn + n] = v;
        else         ((short*)Out)[(size_t)m * Hn + n] = bf16r(v);
    }
}

// ---------------------------------------------------------------------------
// energy_argmax: per (batch, 128-row q-tile, 512-col key-chunk) block,
// computes fp16x2-split QK^T and reduces per-row (max,argmax) with np
// tie-breaking (lowest index). Writes partials (one per key-chunk).
// ---------------------------------------------------------------------------
__global__ __launch_bounds__(256) void energy_argmax(
    const f16* __restrict__ Qh, const f16* __restrict__ Ql,
    const f16* __restrict__ Kh, const f16* __restrict__ Kl,
    const int* __restrict__ mask,
    float* __restrict__ pval, int* __restrict__ pidx)
{
    __shared__ __align__(16) f16 Ah[4096], Al[4096], Bh[4096], Bl[4096];
    __shared__ float maskF[512];
    __shared__ float bwv[2][128];
    __shared__ int   bwi[2][128];
    const int tid = threadIdx.x, lane = tid & 63, wid = tid >> 6;
    const int wr = wid >> 1, wc = wid & 1, l15 = lane & 15, lg = lane >> 4;
    const int qt = blockIdx.x, kc = blockIdx.y, b = blockIdx.z;
    const int m0 = b * Qn + qt * 128;
    const int kbase = kc * 512;
    const float NEGINF = -__builtin_inff();

    // mask==nonzero (true) -> -inf   [assumes bool pushed as int32]
    maskF[tid]       = mask[b * Kn + kbase + tid]       ? NEGINF : 0.0f;
    maskF[tid + 256] = mask[b * Kn + kbase + tid + 256] ? NEGINF : 0.0f;
    if (tid < 128) {
        bwv[0][tid] = NEGINF; bwv[1][tid] = NEGINF;
        bwi[0][tid] = 0x7fffffff; bwi[1][tid] = 0x7fffffff;
    }
    const int sr0 = tid >> 2, sc0 = (tid & 3) * 8;

    #pragma unroll 1
    for (int kt = 0; kt < 4; ++kt) {
        const int kr0 = b * Kn + kbase + kt * 128;
        f32x4 a0[4][4] = {}, a1[4][4] = {};
        #pragma unroll 1
        for (int ks = 0; ks < 16; ++ks) {
            const int k0 = ks * 32;
            __syncthreads();
            #pragma unroll
            for (int rr = 0; rr < 2; ++rr) {
                int row = sr0 + rr * 64;
                size_t ga = (size_t)(m0 + row) * Hn + k0 + sc0;
                size_t gb = (size_t)(kr0 + row) * Hn + k0 + sc0;
                int off = row * 32 + (((sc0 >> 3) ^ (row & 3)) << 3);
                *(f16x8*)&Ah[off] = *(const f16x8*)(Qh + ga);
                *(f16x8*)&Al[off] = *(const f16x8*)(Ql + ga);
                *(f16x8*)&Bh[off] = *(const f16x8*)(Kh + gb);
                *(f16x8*)&Bl[off] = *(const f16x8*)(Kl + gb);
            }
            __syncthreads();
            f16x8 fbh[4], fbl[4];
            #pragma unroll
            for (int fj = 0; fj < 4; ++fj) {
                int row = wc * 64 + fj * 16 + l15;
                int off = row * 32 + ((lg ^ (row & 3)) << 3);
                fbh[fj] = *(f16x8*)&Bh[off];
                fbl[fj] = *(f16x8*)&Bl[off];
            }
            #pragma unroll
            for (int fi = 0; fi < 4; ++fi) {
                int row = wr * 64 + fi * 16 + l15;
                int off = row * 32 + ((lg ^ (row & 3)) << 3);
                f16x8 fah = *(f16x8*)&Ah[off];
                f16x8 fal = *(f16x8*)&Al[off];
                #pragma unroll
                for (int fj = 0; fj < 4; ++fj) {
                    a0[fi][fj] = MFMA16(fah, fbh[fj], a0[fi][fj]);
                    a1[fi][fj] = MFMA16(fah, fbl[fj], a1[fi][fj]);
                    a1[fi][fj] = MFMA16(fal, fbh[fj], a1[fi][fj]);
                }
            }
        }
        // per-row argmax for this 128-col k-tile
        #pragma unroll
        for (int fi = 0; fi < 4; ++fi) {
            #pragma unroll
            for (int j = 0; j < 4; ++j) {
                float bv = NEGINF; int bc = 0x7fffffff;
                #pragma unroll
                for (int fj = 0; fj < 4; ++fj) {
                    int lc = kt * 128 + wc * 64 + fj * 16 + l15;
                    float v = a0[fi][fj][j] + a1[fi][fj][j] * (1.0f / 2048.0f) + maskF[lc];
                    if (v > bv || (v == bv && lc < bc)) { bv = v; bc = lc; }
                }
                #pragma unroll
                for (int sm = 1; sm < 16; sm <<= 1) {
                    float ov = __shfl_xor(bv, sm, 64);
                    int   oc = __shfl_xor(bc, sm, 64);
                    if (ov > bv || (ov == bv && oc < bc)) { bv = ov; bc = oc; }
                }
                if (l15 == 0) {
                    int row = wr * 64 + fi * 16 + lg * 4 + j;
                    if (bv > bwv[wc][row] || (bv == bwv[wc][row] && bc < bwi[wc][row])) {
                        bwv[wc][row] = bv; bwi[wc][row] = bc;
                    }
                }
            }
        }
    }
    __syncthreads();
    if (tid < 128) {
        float v0 = bwv[0][tid], v1 = bwv[1][tid];
        int   i0 = bwi[0][tid], i1 = bwi[1][tid];
        float v; int i;
        if (v0 > v1 || (v0 == v1 && i0 < i1)) { v = v0; i = i0; } else { v = v1; i = i1; }
        int m = m0 + tid;
        pval[m * 4 + kc] = v;
        pidx[m * 4 + kc] = kbase + i;
    }
}

// ---------------------------------------------------------------------------
// merge_gather: merge 4 chunk-partials -> idx; gather Vp row -> Vg.
// One wave per output row.
// ---------------------------------------------------------------------------
__global__ __launch_bounds__(256) void merge_gather(
    const float* __restrict__ pval, const int* __restrict__ pidx,
    const short* __restrict__ Vp, short* __restrict__ Vg, int* __restrict__ idxArr)
{
    int wid = threadIdx.x >> 6, lane = threadIdx.x & 63;
    int m = blockIdx.x * 4 + wid;
    float bv = -__builtin_inff(); int bi = 0x7fffffff;
    #pragma unroll
    for (int c = 0; c < 4; ++c) {
        float v = pval[m * 4 + c]; int i = pidx[m * 4 + c];
        if (v > bv || (v == bv && i < bi)) { bv = v; bi = i; }
    }
    if (lane == 0) idxArr[m] = bi;
    int b = m >> 11;
    size_t src = ((size_t)(b * Kn + bi)) * Hn + lane * 8;
    size_t dst = (size_t)m * Hn + lane * 8;
    *(s16x8*)(Vg + dst) = *(const s16x8*)(Vp + src);
}

// ---------------------------------------------------------------------------
// score_fill: one-hot rows (writes the ENTIRE score region, erasing scratch).
// ---------------------------------------------------------------------------
__global__ __launch_bounds__(256) void score_fill(
    const int* __restrict__ idxArr, float* __restrict__ score)
{
    int m = blockIdx.x;
    int c = idxArr[m];
    float* row = score + (size_t)m * Kn;
    int t = threadIdx.x;
    #pragma unroll
    for (int i = 0; i < 2; ++i) {
        int v = t + i * 256;
        f32x4 val = {0.f, 0.f, 0.f, 0.f};
        if ((c >> 2) == v) val[c & 3] = 1.0f;
        *(f32x4*)(row + v * 4) = val;
    }
}

// ---------------------------------------------------------------------------
extern "C" void kernel_launch(void* const* d_in, const int* in_sizes, int n_in,
                              void* d_out, int out_size, void* d_ws, size_t ws_size,
                              hipStream_t stream)
{
    const float* query = (const float*)d_in[0];
    const float* key_  = (const float*)d_in[1];
    const float* value = (const float*)d_in[2];
    const int*   mask  = (const int*)d_in[3];
    const float* Wq = (const float*)d_in[4];
    const float* bq = (const float*)d_in[5];
    const float* Wk = (const float*)d_in[6];
    const float* bk = (const float*)d_in[7];
    const float* Wv = (const float*)d_in[8];
    const float* bv = (const float*)d_in[9];
    const float* Wo = (const float*)d_in[10];
    const float* bo = (const float*)d_in[11];

    float* res = (float*)d_out;                       // (B,Q,H) f32
    float* scoreBase = res + (size_t)Mn * Hn;         // (B,Q,K) f32, 134 MB
    char* sc = (char*)scoreBase;                      // scratch inside score region
    const size_t MB16 = (size_t)Mn * Hn * 2;          // 16,777,216 B
    f16*   Qp_h = (f16*)(sc + 0 * MB16);
    f16*   Qp_l = (f16*)(sc + 1 * MB16);
    f16*   Kp_h = (f16*)(sc + 2 * MB16);
    f16*   Kp_l = (f16*)(sc + 3 * MB16);
    short* Vp   = (short*)(sc + 4 * MB16);
    char*  wb   = sc + 5 * MB16;
    f16*   Wqth = (f16*)(wb + 0 * 524288);
    f16*   Wqtl = (f16*)(wb + 1 * 524288);
    f16*   Wkth = (f16*)(wb + 2 * 524288);
    f16*   Wktl = (f16*)(wb + 3 * 524288);
    short* Wvt  = (short*)(wb + 4 * 524288);
    short* Wot  = (short*)(wb + 5 * 524288);
    short* Vg   = (short*)(sc + 0 * MB16);            // reuse Qp_h (dead after energy)

    float* pval   = (float*)d_ws;                     // Mn*4
    int*   pidx   = (int*)d_ws + 65536;               // Mn*4
    int*   idxArr = (int*)d_ws + 131072;              // Mn

    prep_w<<<1024, 256, 0, stream>>>(Wq, Wk, Wv, Wo, Wqth, Wqtl, Wkth, Wktl, Wvt, Wot);

    dim3 gP(Mn / 128, Hn / 128);
    proj_split<<<gP, 256, 0, stream>>>(query, Wqth, Wqtl, bq, Qp_h, Qp_l);
    proj_split<<<gP, 256, 0, stream>>>(key_,  Wkth, Wktl, bk, Kp_h, Kp_l);
    gemm_bf<1, 0><<<gP, 256, 0, stream>>>(value, Wvt, bv, Vp);

    energy_argmax<<<dim3(Qn / 128, 4, Bn), 256, 0, stream>>>(
        Qp_h, Qp_l, Kp_h, Kp_l, mask, pval, pidx);

    merge_gather<<<Mn / 4, 256, 0, stream>>>(pval, pidx, Vp, Vg, idxArr);

    gemm_bf<0, 1><<<gP, 256, 0, stream>>>(Vg, Wot, bo, res);

    score_fill<<<Mn, 256, 0, stream>>>(idxArr, scoreBase);
}

// Round 2
// 442.950 us; speedup vs baseline: 1.0099x; 1.0099x over previous
//
#include <hip/hip_runtime.h>

typedef _Float16 f16;
typedef f16 f16x8 __attribute__((ext_vector_type(8)));
typedef f16 f16x4 __attribute__((ext_vector_type(4)));
typedef short s16x8 __attribute__((ext_vector_type(8)));
typedef short s16x4 __attribute__((ext_vector_type(4)));
typedef float f32x4 __attribute__((ext_vector_type(4)));

#define MFMA16(a,b,c)  __builtin_amdgcn_mfma_f32_16x16x32_f16(a,b,c,0,0,0)
#define MFMAB16(a,b,c) __builtin_amdgcn_mfma_f32_16x16x32_bf16(a,b,c,0,0,0)

static constexpr int Bn = 8, Qn = 2048, Kn = 2048, Hn = 512;
static constexpr int Mn = Bn * Qn;           // 16384 flat rows

__device__ __forceinline__ short bf16r(float x) {
    unsigned u = __builtin_bit_cast(unsigned, x);
    u += 0x7fffu + ((u >> 16) & 1u);
    return (short)(u >> 16);
}

// ---------------------------------------------------------------------------
// compact_mask: per batch, order-preserving list of unmasked key indices.
// cidx[b][j] = j-th original key index with mask==0; cnt[b] = count (>=1).
// ---------------------------------------------------------------------------
__global__ __launch_bounds__(256) void compact_mask(
    const int* __restrict__ mask, int* __restrict__ cidx, int* __restrict__ cnt)
{
    __shared__ int sums[256];
    int b = blockIdx.x, t = threadIdx.x;
    int base = b * Kn + t * 8;
    int mv[8]; int s = 0;
    #pragma unroll
    for (int i = 0; i < 8; ++i) { mv[i] = (mask[base + i] == 0); s += mv[i]; }
    sums[t] = s;
    __syncthreads();
    for (int off = 1; off < 256; off <<= 1) {
        int v = (t >= off) ? sums[t - off] : 0;
        __syncthreads();
        sums[t] += v;
        __syncthreads();
    }
    int pos = (t > 0 ? sums[t - 1] : 0);
    #pragma unroll
    for (int i = 0; i < 8; ++i)
        if (mv[i]) cidx[b * Kn + pos++] = t * 8 + i;
    if (t == 255) {
        int total = sums[255];
        if (total == 0) { cidx[b * Kn] = 0; total = 1; }  // all-masked insurance
        cnt[b] = total;
    }
}

// ---------------------------------------------------------------------------
// prep_w: transposed/split weights. Wq/Wk -> fp16 hi + lo*2^11 (x512 scale);
// Wv/Wo -> bf16.
// ---------------------------------------------------------------------------
__global__ __launch_bounds__(256) void prep_w(
    const float* __restrict__ Wq, const float* __restrict__ Wk,
    const float* __restrict__ Wv, const float* __restrict__ Wo,
    f16* __restrict__ Wqth, f16* __restrict__ Wqtl,
    f16* __restrict__ Wkth, f16* __restrict__ Wktl,
    short* __restrict__ Wvt, short* __restrict__ Wot)
{
    int e = blockIdx.x * 256 + threadIdx.x;
    int k = e >> 9, n = e & 511;
    int s = k * 512 + n, d = n * 512 + k;
    float wq = Wq[s] * 512.0f;
    f16 h = (f16)wq;
    Wqth[d] = h; Wqtl[d] = (f16)((wq - (float)h) * 2048.0f);
    float wk = Wk[s] * 512.0f;
    h = (f16)wk;
    Wkth[d] = h; Wktl[d] = (f16)((wk - (float)h) * 2048.0f);
    Wvt[d] = bf16r(Wv[s]);
    Wot[d] = bf16r(Wo[s]);
}

// ---------------------------------------------------------------------------
// proj_split: P = (A @ Wt^T)/512 + bias -> fp16 hi/lo pair.
// INDIRECT: A rows gathered via cidx (compacted keys), early-exit past cnt.
// ---------------------------------------------------------------------------
template<int INDIRECT>
__global__ __launch_bounds__(256) void proj_split(
    const float* __restrict__ A,
    const f16* __restrict__ Bth, const f16* __restrict__ Btl,
    const float* __restrict__ bias,
    f16* __restrict__ Ph, f16* __restrict__ Pl,
    const int* __restrict__ cidx, const int* __restrict__ cnt)
{
    __shared__ __align__(16) f16 Ah[4096], Al[4096], Bh[4096], Bl[4096];
    const int tid = threadIdx.x, lane = tid & 63, wid = tid >> 6;
    const int wr = wid >> 1, wc = wid & 1, l15 = lane & 15, lg = lane >> 4;
    const int m0 = blockIdx.x * 128, n0 = blockIdx.y * 128;
    const int b = m0 >> 11, m0l = m0 & 2047;
    int cn = 0;
    if (INDIRECT) {
        cn = cnt[b];
        if (m0l >= cn) return;
    }
    f32x4 a0[4][4] = {}, a1[4][4] = {};
    const int ar0 = tid >> 3, ac0 = (tid & 7) * 4;
    const int br0 = tid >> 2, bc0 = (tid & 3) * 8;

    #pragma unroll 1
    for (int ks = 0; ks < 16; ++ks) {
        const int k0 = ks * 32;
        __syncthreads();
        #pragma unroll
        for (int rr = 0; rr < 4; ++rr) {
            int row = ar0 + rr * 32;
            size_t srow;
            if (INDIRECT) {
                int r = m0l + row;
                int cid = (r < cn) ? cidx[b * Kn + r] : 0;
                srow = (size_t)(b * Kn + cid);
            } else {
                srow = (size_t)(m0 + row);
            }
            f32x4 v = *(const f32x4*)(A + srow * Hn + k0 + ac0);
            f16x4 oh, ol;
            #pragma unroll
            for (int j = 0; j < 4; ++j) {
                f16 hh = (f16)v[j];
                oh[j] = hh;
                ol[j] = (f16)((v[j] - (float)hh) * 2048.0f);
            }
            int off = row * 32 + (((ac0 >> 3) ^ (row & 3)) << 3) + (ac0 & 7);
            *(f16x4*)&Ah[off] = oh;
            *(f16x4*)&Al[off] = ol;
        }
        #pragma unroll
        for (int rr = 0; rr < 2; ++rr) {
            int row = br0 + rr * 64;
            size_t g = (size_t)(n0 + row) * Hn + k0 + bc0;
            int off = row * 32 + (((bc0 >> 3) ^ (row & 3)) << 3);
            *(f16x8*)&Bh[off] = *(const f16x8*)(Bth + g);
            *(f16x8*)&Bl[off] = *(const f16x8*)(Btl + g);
        }
        __syncthreads();
        f16x8 fbh[4], fbl[4];
        #pragma unroll
        for (int fj = 0; fj < 4; ++fj) {
            int row = wc * 64 + fj * 16 + l15;
            int off = row * 32 + ((lg ^ (row & 3)) << 3);
            fbh[fj] = *(f16x8*)&Bh[off];
            fbl[fj] = *(f16x8*)&Bl[off];
        }
        #pragma unroll
        for (int fi = 0; fi < 4; ++fi) {
            int row = wr * 64 + fi * 16 + l15;
            int off = row * 32 + ((lg ^ (row & 3)) << 3);
            f16x8 fah = *(f16x8*)&Ah[off];
            f16x8 fal = *(f16x8*)&Al[off];
            #pragma unroll
            for (int fj = 0; fj < 4; ++fj) {
                a0[fi][fj] = MFMA16(fah, fbh[fj], a0[fi][fj]);
                a1[fi][fj] = MFMA16(fah, fbl[fj], a1[fi][fj]);
                a1[fi][fj] = MFMA16(fal, fbh[fj], a1[fi][fj]);
            }
        }
    }
    #pragma unroll
    for (int fi = 0; fi < 4; ++fi)
    #pragma unroll
    for (int fj = 0; fj < 4; ++fj)
    #pragma unroll
    for (int j = 0; j < 4; ++j) {
        int m = m0 + wr * 64 + fi * 16 + lg * 4 + j;
        int n = n0 + wc * 64 + fj * 16 + l15;
        float v = (a0[fi][fj][j] + a1[fi][fj][j] * (1.0f / 2048.0f)) * (1.0f / 512.0f) + bias[n];
        f16 h = (f16)v;
        Ph[(size_t)m * Hn + n] = h;
        Pl[(size_t)m * Hn + n] = (f16)((v - (float)h) * 2048.0f);
    }
}

// ---------------------------------------------------------------------------
// gemm_bf: bf16 GEMM_BT, C = A @ Bt^T + bias.
// ---------------------------------------------------------------------------
template<int A_F32, int OUT_F32, int INDIRECT>
__global__ __launch_bounds__(256) void gemm_bf(
    const void* __restrict__ Asrc, const short* __restrict__ Bt,
    const float* __restrict__ bias, void* __restrict__ Out,
    const int* __restrict__ cidx, const int* __restrict__ cnt)
{
    __shared__ __align__(16) short As[4096], Bs[4096];
    const int tid = threadIdx.x, lane = tid & 63, wid = tid >> 6;
    const int wr = wid >> 1, wc = wid & 1, l15 = lane & 15, lg = lane >> 4;
    const int m0 = blockIdx.x * 128, n0 = blockIdx.y * 128;
    const int b = m0 >> 11, m0l = m0 & 2047;
    int cn = 0;
    if (INDIRECT) {
        cn = cnt[b];
        if (m0l >= cn) return;
    }
    f32x4 acc[4][4] = {};
    const int ar0 = tid >> 3, ac0 = (tid & 7) * 4;
    const int br0 = tid >> 2, bc0 = (tid & 3) * 8;

    #pragma unroll 1
    for (int ks = 0; ks < 16; ++ks) {
        const int k0 = ks * 32;
        __syncthreads();
        if (A_F32) {
            #pragma unroll
            for (int rr = 0; rr < 4; ++rr) {
                int row = ar0 + rr * 32;
                size_t srow;
                if (INDIRECT) {
                    int r = m0l + row;
                    int cid = (r < cn) ? cidx[b * Kn + r] : 0;
                    srow = (size_t)(b * Kn + cid);
                } else {
                    srow = (size_t)(m0 + row);
                }
                f32x4 v = *(const f32x4*)((const float*)Asrc + srow * Hn + k0 + ac0);
                s16x4 o;
                #pragma unroll
                for (int j = 0; j < 4; ++j) o[j] = bf16r(v[j]);
                int off = row * 32 + (((ac0 >> 3) ^ (row & 3)) << 3) + (ac0 & 7);
                *(s16x4*)&As[off] = o;
            }
        } else {
            #pragma unroll
            for (int rr = 0; rr < 2; ++rr) {
                int row = br0 + rr * 64;
                int off = row * 32 + (((bc0 >> 3) ^ (row & 3)) << 3);
                *(s16x8*)&As[off] = *(const s16x8*)((const short*)Asrc + (size_t)(m0 + row) * Hn + k0 + bc0);
            }
        }
        #pragma unroll
        for (int rr = 0; rr < 2; ++rr) {
            int row = br0 + rr * 64;
            int off = row * 32 + (((bc0 >> 3) ^ (row & 3)) << 3);
            *(s16x8*)&Bs[off] = *(const s16x8*)(Bt + (size_t)(n0 + row) * Hn + k0 + bc0);
        }
        __syncthreads();
        s16x8 fb[4];
        #pragma unroll
        for (int fj = 0; fj < 4; ++fj) {
            int row = wc * 64 + fj * 16 + l15;
            fb[fj] = *(s16x8*)&Bs[row * 32 + ((lg ^ (row & 3)) << 3)];
        }
        #pragma unroll
        for (int fi = 0; fi < 4; ++fi) {
            int row = wr * 64 + fi * 16 + l15;
            s16x8 fa = *(s16x8*)&As[row * 32 + ((lg ^ (row & 3)) << 3)];
            #pragma unroll
            for (int fj = 0; fj < 4; ++fj)
                acc[fi][fj] = MFMAB16(fa, fb[fj], acc[fi][fj]);
        }
    }
    #pragma unroll
    for (int fi = 0; fi < 4; ++fi)
    #pragma unroll
    for (int fj = 0; fj < 4; ++fj)
    #pragma unroll
    for (int j = 0; j < 4; ++j) {
        int m = m0 + wr * 64 + fi * 16 + lg * 4 + j;
        int n = n0 + wc * 64 + fj * 16 + l15;
        float v = acc[fi][fj][j] + bias[n];
        if (OUT_F32) ((float*)Out)[(size_t)m * Hn + n] = v;
        else         ((short*)Out)[(size_t)m * Hn + n] = bf16r(v);
    }
}

// ---------------------------------------------------------------------------
// energy_argmax: per (128-q-tile, 256-key-chunk of COMPACTED keys, batch).
// fp16x2-split QK^T; per-row (max, argmax) partials in compacted space.
// ---------------------------------------------------------------------------
__global__ __launch_bounds__(256) void energy_argmax(
    const f16* __restrict__ Qh, const f16* __restrict__ Ql,
    const f16* __restrict__ Kh, const f16* __restrict__ Kl,
    const int* __restrict__ cnt,
    float* __restrict__ pval, int* __restrict__ pidx)
{
    __shared__ __align__(16) f16 Ah[4096], Al[4096], Bh[4096], Bl[4096];
    __shared__ float maskF[256];
    __shared__ float bwv[2][128];
    __shared__ int   bwi[2][128];
    const int tid = threadIdx.x, lane = tid & 63, wid = tid >> 6;
    const int wr = wid >> 1, wc = wid & 1, l15 = lane & 15, lg = lane >> 4;
    const int qt = blockIdx.x, kc = blockIdx.y, b = blockIdx.z;
    const int cn = cnt[b];
    const int kbase = kc * 256;
    if (kbase >= cn) return;
    const int m0 = b * Qn + qt * 128;
    const float NEGINF = -__builtin_inff();

    maskF[tid & 255] = (kbase + (tid & 255) < cn) ? 0.0f : NEGINF;
    if (tid < 128) {
        bwv[0][tid] = NEGINF; bwv[1][tid] = NEGINF;
        bwi[0][tid] = 0x7fffffff; bwi[1][tid] = 0x7fffffff;
    }
    const int sr0 = tid >> 2, sc0 = (tid & 3) * 8;

    #pragma unroll 1
    for (int kt = 0; kt < 2; ++kt) {
        if (kbase + kt * 128 >= cn) break;       // block-uniform
        const int kr0 = b * Kn + kbase + kt * 128;
        f32x4 a0[4][4] = {}, a1[4][4] = {};
        #pragma unroll 1
        for (int ks = 0; ks < 16; ++ks) {
            const int k0 = ks * 32;
            __syncthreads();
            #pragma unroll
            for (int rr = 0; rr < 2; ++rr) {
                int row = sr0 + rr * 64;
                size_t ga = (size_t)(m0 + row) * Hn + k0 + sc0;
                size_t gb = (size_t)(kr0 + row) * Hn + k0 + sc0;
                int off = row * 32 + (((sc0 >> 3) ^ (row & 3)) << 3);
                *(f16x8*)&Ah[off] = *(const f16x8*)(Qh + ga);
                *(f16x8*)&Al[off] = *(const f16x8*)(Ql + ga);
                *(f16x8*)&Bh[off] = *(const f16x8*)(Kh + gb);
                *(f16x8*)&Bl[off] = *(const f16x8*)(Kl + gb);
            }
            __syncthreads();
            f16x8 fbh[4], fbl[4];
            #pragma unroll
            for (int fj = 0; fj < 4; ++fj) {
                int row = wc * 64 + fj * 16 + l15;
                int off = row * 32 + ((lg ^ (row & 3)) << 3);
                fbh[fj] = *(f16x8*)&Bh[off];
                fbl[fj] = *(f16x8*)&Bl[off];
            }
            #pragma unroll
            for (int fi = 0; fi < 4; ++fi) {
                int row = wr * 64 + fi * 16 + l15;
                int off = row * 32 + ((lg ^ (row & 3)) << 3);
                f16x8 fah = *(f16x8*)&Ah[off];
                f16x8 fal = *(f16x8*)&Al[off];
                #pragma unroll
                for (int fj = 0; fj < 4; ++fj) {
                    a0[fi][fj] = MFMA16(fah, fbh[fj], a0[fi][fj]);
                    a1[fi][fj] = MFMA16(fah, fbl[fj], a1[fi][fj]);
                    a1[fi][fj] = MFMA16(fal, fbh[fj], a1[fi][fj]);
                }
            }
        }
        #pragma unroll
        for (int fi = 0; fi < 4; ++fi) {
            #pragma unroll
            for (int j = 0; j < 4; ++j) {
                float bv = NEGINF; int bc = 0x7fffffff;
                #pragma unroll
                for (int fj = 0; fj < 4; ++fj) {
                    int lc = kt * 128 + wc * 64 + fj * 16 + l15;
                    float v = a0[fi][fj][j] + a1[fi][fj][j] * (1.0f / 2048.0f) + maskF[lc];
                    if (v > bv || (v == bv && lc < bc)) { bv = v; bc = lc; }
                }
                #pragma unroll
                for (int sm = 1; sm < 16; sm <<= 1) {
                    float ov = __shfl_xor(bv, sm, 64);
                    int   oc = __shfl_xor(bc, sm, 64);
                    if (ov > bv || (ov == bv && oc < bc)) { bv = ov; bc = oc; }
                }
                if (l15 == 0) {
                    int row = wr * 64 + fi * 16 + lg * 4 + j;
                    if (bv > bwv[wc][row] || (bv == bwv[wc][row] && bc < bwi[wc][row])) {
                        bwv[wc][row] = bv; bwi[wc][row] = bc;
                    }
                }
            }
        }
    }
    __syncthreads();
    if (tid < 128) {
        float v0 = bwv[0][tid], v1 = bwv[1][tid];
        int   i0 = bwi[0][tid], i1 = bwi[1][tid];
        float v; int i;
        if (v0 > v1 || (v0 == v1 && i0 < i1)) { v = v0; i = i0; } else { v = v1; i = i1; }
        int m = m0 + tid;
        pval[m * 8 + kc] = v;
        pidx[m * 8 + kc] = kbase + i;
    }
}

// ---------------------------------------------------------------------------
// merge_gather: merge active chunk partials -> compacted argmax; gather Vc
// row -> Vg; map to original index for score.
// ---------------------------------------------------------------------------
__global__ __launch_bounds__(256) void merge_gather(
    const float* __restrict__ pval, const int* __restrict__ pidx,
    const int* __restrict__ cnt, const int* __restrict__ cidx,
    const short* __restrict__ Vc, short* __restrict__ Vg, int* __restrict__ idxArr)
{
    int wid = threadIdx.x >> 6, lane = threadIdx.x & 63;
    int m = blockIdx.x * 4 + wid;
    int b = m >> 11;
    int nc = (cnt[b] + 255) >> 8;
    float bv = -__builtin_inff(); int bi = 0x7fffffff;
    for (int c = 0; c < nc; ++c) {
        float v = pval[m * 8 + c]; int i = pidx[m * 8 + c];
        if (v > bv || (v == bv && i < bi)) { bv = v; bi = i; }
    }
    if (lane == 0) idxArr[m] = cidx[b * Kn + bi];
    size_t src = ((size_t)(b * Kn + bi)) * Hn + lane * 8;
    size_t dst = (size_t)m * Hn + lane * 8;
    *(s16x8*)(Vg + dst) = *(const s16x8*)(Vc + src);
}

// ---------------------------------------------------------------------------
// score_fill: one-hot rows (writes ENTIRE score region, erasing scratch).
// ---------------------------------------------------------------------------
__global__ __launch_bounds__(256) void score_fill(
    const int* __restrict__ idxArr, float* __restrict__ score)
{
    int m = blockIdx.x;
    int c = idxArr[m];
    float* row = score + (size_t)m * Kn;
    int t = threadIdx.x;
    #pragma unroll
    for (int i = 0; i < 2; ++i) {
        int v = t + i * 256;
        f32x4 val = {0.f, 0.f, 0.f, 0.f};
        if ((c >> 2) == v) val[c & 3] = 1.0f;
        *(f32x4*)(row + v * 4) = val;
    }
}

// ---------------------------------------------------------------------------
extern "C" void kernel_launch(void* const* d_in, const int* in_sizes, int n_in,
                              void* d_out, int out_size, void* d_ws, size_t ws_size,
                              hipStream_t stream)
{
    const float* query = (const float*)d_in[0];
    const float* key_  = (const float*)d_in[1];
    const float* value = (const float*)d_in[2];
    const int*   mask  = (const int*)d_in[3];
    const float* Wq = (const float*)d_in[4];
    const float* bq = (const float*)d_in[5];
    const float* Wk = (const float*)d_in[6];
    const float* bk = (const float*)d_in[7];
    const float* Wv = (const float*)d_in[8];
    const float* bv = (const float*)d_in[9];
    const float* Wo = (const float*)d_in[10];
    const float* bo = (const float*)d_in[11];

    float* res = (float*)d_out;                       // (B,Q,H) f32
    float* scoreBase = res + (size_t)Mn * Hn;         // (B,Q,K) f32, 134 MB
    char* sc = (char*)scoreBase;                      // scratch inside score region
    const size_t MB16 = (size_t)Mn * Hn * 2;          // 16 MiB
    f16*   Qp_h = (f16*)(sc + 0 * MB16);
    f16*   Qp_l = (f16*)(sc + 1 * MB16);
    f16*   Kc_h = (f16*)(sc + 2 * MB16);
    f16*   Kc_l = (f16*)(sc + 3 * MB16);
    short* Vc   = (short*)(sc + 4 * MB16);
    char*  wb   = sc + 5 * MB16;
    f16*   Wqth = (f16*)(wb + 0 * 524288);
    f16*   Wqtl = (f16*)(wb + 1 * 524288);
    f16*   Wkth = (f16*)(wb + 2 * 524288);
    f16*   Wktl = (f16*)(wb + 3 * 524288);
    short* Wvt  = (short*)(wb + 4 * 524288);
    short* Wot  = (short*)(wb + 5 * 524288);
    int*   cidx = (int*)(wb + 6 * 524288);            // 8*2048 ints = 64 KB
    float* pval = (float*)(wb + 6 * 524288 + 65536);  // Mn*8 f32 = 512 KB
    int*   pidx = (int*)(wb + 6 * 524288 + 65536 + 524288);
    short* Vg   = (short*)(sc + 0 * MB16);            // reuse Qp_h after energy

    int*   idxArr = (int*)d_ws;                       // Mn ints (read by score_fill)
    int*   cnt    = (int*)d_ws + Mn;                  // 8 ints

    compact_mask<<<Bn, 256, 0, stream>>>(mask, cidx, cnt);
    prep_w<<<1024, 256, 0, stream>>>(Wq, Wk, Wv, Wo, Wqth, Wqtl, Wkth, Wktl, Wvt, Wot);

    dim3 gP(Mn / 128, Hn / 128);
    proj_split<0><<<gP, 256, 0, stream>>>(query, Wqth, Wqtl, bq, Qp_h, Qp_l, nullptr, nullptr);
    proj_split<1><<<gP, 256, 0, stream>>>(key_,  Wkth, Wktl, bk, Kc_h, Kc_l, cidx, cnt);
    gemm_bf<1, 0, 1><<<gP, 256, 0, stream>>>(value, Wvt, bv, Vc, cidx, cnt);

    energy_argmax<<<dim3(Qn / 128, 8, Bn), 256, 0, stream>>>(
        Qp_h, Qp_l, Kc_h, Kc_l, cnt, pval, pidx);

    merge_gather<<<Mn / 4, 256, 0, stream>>>(pval, pidx, cnt, cidx, Vc, Vg, idxArr);

    gemm_bf<0, 1, 0><<<gP, 256, 0, stream>>>(Vg, Wot, bo, res, nullptr, nullptr);

    score_fill<<<Mn, 256, 0, stream>>>(idxArr, scoreBase);
}

// Round 3
// 310.792 us; speedup vs baseline: 1.4393x; 1.4252x over previous
//
#include <hip/hip_runtime.h>

typedef _Float16 f16;
typedef f16 f16x8 __attribute__((ext_vector_type(8)));
typedef f16 f16x4 __attribute__((ext_vector_type(4)));
typedef short s16x8 __attribute__((ext_vector_type(8)));
typedef short s16x4 __attribute__((ext_vector_type(4)));
typedef float f32x4 __attribute__((ext_vector_type(4)));

#define MFMA16(a,b,c)  __builtin_amdgcn_mfma_f32_16x16x32_f16(a,b,c,0,0,0)
#define MFMAB16(a,b,c) __builtin_amdgcn_mfma_f32_16x16x32_bf16(a,b,c,0,0,0)

static constexpr int Bn = 8, Qn = 2048, Kn = 2048, Hn = 512;
static constexpr int Mn = Bn * Qn;           // 16384 flat rows

typedef __attribute__((address_space(1))) const unsigned int as1_uint;
typedef __attribute__((address_space(3))) unsigned int as3_uint;

// async 16B/lane global->LDS: lds base wave-uniform (HW adds lane*16),
// global address per-lane (enables source-side swizzle).
__device__ __forceinline__ void gl_lds16(const void* g, void* l) {
    __builtin_amdgcn_global_load_lds((as1_uint*)g, (as3_uint*)l, 16, 0, 0);
}

__device__ __forceinline__ short bf16r(float x) {
    unsigned u = __builtin_bit_cast(unsigned, x);
    u += 0x7fffu + ((u >> 16) & 1u);
    return (short)(u >> 16);
}

// ---------------------------------------------------------------------------
// compact_mask: per batch, order-preserving list of unmasked key indices.
// ---------------------------------------------------------------------------
__global__ __launch_bounds__(256) void compact_mask(
    const int* __restrict__ mask, int* __restrict__ cidx, int* __restrict__ cnt)
{
    __shared__ int sums[256];
    int b = blockIdx.x, t = threadIdx.x;
    int base = b * Kn + t * 8;
    int mv[8]; int s = 0;
    #pragma unroll
    for (int i = 0; i < 8; ++i) { mv[i] = (mask[base + i] == 0); s += mv[i]; }
    sums[t] = s;
    __syncthreads();
    for (int off = 1; off < 256; off <<= 1) {
        int v = (t >= off) ? sums[t - off] : 0;
        __syncthreads();
        sums[t] += v;
        __syncthreads();
    }
    int pos = (t > 0 ? sums[t - 1] : 0);
    #pragma unroll
    for (int i = 0; i < 8; ++i)
        if (mv[i]) cidx[b * Kn + pos++] = t * 8 + i;
    if (t == 255) {
        int total = sums[255];
        if (total == 0) { cidx[b * Kn] = 0; total = 1; }
        cnt[b] = total;
    }
}

// ---------------------------------------------------------------------------
// prep_w: transposed/split weights. Wq/Wk -> fp16 hi + lo*2^11 (x512 scale);
// Wv/Wo -> bf16.
// ---------------------------------------------------------------------------
__global__ __launch_bounds__(256) void prep_w(
    const float* __restrict__ Wq, const float* __restrict__ Wk,
    const float* __restrict__ Wv, const float* __restrict__ Wo,
    f16* __restrict__ Wqth, f16* __restrict__ Wqtl,
    f16* __restrict__ Wkth, f16* __restrict__ Wktl,
    short* __restrict__ Wvt, short* __restrict__ Wot)
{
    int e = blockIdx.x * 256 + threadIdx.x;
    int k = e >> 9, n = e & 511;
    int s = k * 512 + n, d = n * 512 + k;
    float wq = Wq[s] * 512.0f;
    f16 h = (f16)wq;
    Wqth[d] = h; Wqtl[d] = (f16)((wq - (float)h) * 2048.0f);
    float wk = Wk[s] * 512.0f;
    h = (f16)wk;
    Wkth[d] = h; Wktl[d] = (f16)((wk - (float)h) * 2048.0f);
    Wvt[d] = bf16r(Wv[s]);
    Wot[d] = bf16r(Wo[s]);
}

// ---------------------------------------------------------------------------
// proj_fused: z=0 Q-proj (split out), z=1 K-proj (indirect, split out),
// z=2 V-proj (indirect, bf16 out). 128x128 tile, dbuf LDS, async B staging.
// ---------------------------------------------------------------------------
__global__ __launch_bounds__(256) void proj_fused(
    const float* __restrict__ query, const float* __restrict__ key_,
    const float* __restrict__ value,
    const f16* __restrict__ Wqth, const f16* __restrict__ Wqtl,
    const f16* __restrict__ Wkth, const f16* __restrict__ Wktl,
    const short* __restrict__ Wvt,
    const float* __restrict__ bq, const float* __restrict__ bk,
    const float* __restrict__ bvec,
    f16* __restrict__ Qp_h, f16* __restrict__ Qp_l,
    f16* __restrict__ Kc_h, f16* __restrict__ Kc_l,
    short* __restrict__ Vc,
    const int* __restrict__ cidx, const int* __restrict__ cnt)
{
    __shared__ __align__(16) char smem[65536];
    const int which = blockIdx.z;
    const int tid = threadIdx.x, lane = tid & 63, wid = tid >> 6;
    const int wr = wid >> 1, wc = wid & 1, l15 = lane & 15, lg = lane >> 4;
    const int m0 = blockIdx.x * 128, n0 = blockIdx.y * 128;
    const int b = m0 >> 11, m0l = m0 & 2047;
    const int srow = lane >> 2, sg = lane & 3;
    const int ar0 = tid >> 3, ac0 = (tid & 7) * 4;

    int cn = 0;
    if (which > 0) {
        cn = cnt[b];
        if (m0l >= cn) return;
    }
    // hoisted A source row pointers (gather once)
    const float* Aptr = (which == 0) ? query : (which == 1 ? key_ : value);
    const float* aSrc[4];
    #pragma unroll
    for (int rr = 0; rr < 4; ++rr) {
        int row = ar0 + rr * 32;
        size_t grow;
        if (which > 0) {
            int r = m0l + row;
            int cid = (r < cn) ? cidx[b * Kn + r] : 0;
            grow = (size_t)(b * Kn + cid);
        } else {
            grow = (size_t)(m0 + row);
        }
        aSrc[rr] = Aptr + grow * Hn;
    }

    if (which < 2) {
        // ---- fp16x2-split projection ----
        f16 (*Ah)[4096] = (f16(*)[4096])(smem);
        f16 (*Al)[4096] = (f16(*)[4096])(smem + 16384);
        f16 (*Bh)[4096] = (f16(*)[4096])(smem + 32768);
        f16 (*Bl)[4096] = (f16(*)[4096])(smem + 49152);
        const f16* Bth = (which == 0) ? Wqth : Wkth;
        const f16* Btl = (which == 0) ? Wqtl : Wktl;
        const float* bias = (which == 0) ? bq : bk;
        f16* Ph = (which == 0) ? Qp_h : Kc_h;
        f16* Pl = (which == 0) ? Qp_l : Kc_l;

        auto stageB = [&](int buf, int ks) {
            const int k0 = ks << 5;
            #pragma unroll
            for (int h = 0; h < 2; ++h) {
                int s = wid + h * 4;
                int row = s * 16 + srow;
                int goff = k0 + ((sg ^ (row & 3)) << 3);
                gl_lds16(Bth + (size_t)(n0 + row) * Hn + goff, &Bh[buf][s * 512]);
                gl_lds16(Btl + (size_t)(n0 + row) * Hn + goff, &Bl[buf][s * 512]);
            }
        };
        auto writeA = [&](int buf, const f32x4* av) {
            #pragma unroll
            for (int rr = 0; rr < 4; ++rr) {
                int row = ar0 + rr * 32;
                f16x4 oh, ol;
                #pragma unroll
                for (int j = 0; j < 4; ++j) {
                    f16 hh = (f16)av[rr][j];
                    oh[j] = hh;
                    ol[j] = (f16)((av[rr][j] - (float)hh) * 2048.0f);
                }
                int off = row * 32 + (((ac0 >> 3) ^ (row & 3)) << 3) + (ac0 & 7);
                *(f16x4*)&Ah[buf][off] = oh;
                *(f16x4*)&Al[buf][off] = ol;
            }
        };

        f32x4 a0[4][4] = {}, a1[4][4] = {};
        {   // prologue: stage buf0
            f32x4 av[4];
            #pragma unroll
            for (int rr = 0; rr < 4; ++rr) av[rr] = *(const f32x4*)(aSrc[rr] + ac0);
            stageB(0, 0);
            writeA(0, av);
        }
        __syncthreads();
        #pragma unroll 1
        for (int ks = 0; ks < 16; ++ks) {
            const int cur = ks & 1, nxt = cur ^ 1;
            f32x4 av[4];
            if (ks < 15) {
                const int k1 = (ks + 1) << 5;
                #pragma unroll
                for (int rr = 0; rr < 4; ++rr) av[rr] = *(const f32x4*)(aSrc[rr] + k1 + ac0);
                stageB(nxt, ks + 1);
            }
            f16x8 fbh[4], fbl[4];
            #pragma unroll
            for (int fj = 0; fj < 4; ++fj) {
                int row = wc * 64 + fj * 16 + l15;
                int off = row * 32 + ((lg ^ (row & 3)) << 3);
                fbh[fj] = *(f16x8*)&Bh[cur][off];
                fbl[fj] = *(f16x8*)&Bl[cur][off];
            }
            #pragma unroll
            for (int fi = 0; fi < 4; ++fi) {
                int row = wr * 64 + fi * 16 + l15;
                int off = row * 32 + ((lg ^ (row & 3)) << 3);
                f16x8 fah = *(f16x8*)&Ah[cur][off];
                f16x8 fal = *(f16x8*)&Al[cur][off];
                #pragma unroll
                for (int fj = 0; fj < 4; ++fj) {
                    a0[fi][fj] = MFMA16(fah, fbh[fj], a0[fi][fj]);
                    a1[fi][fj] = MFMA16(fah, fbl[fj], a1[fi][fj]);
                    a1[fi][fj] = MFMA16(fal, fbh[fj], a1[fi][fj]);
                }
            }
            if (ks < 15) writeA(nxt, av);
            __syncthreads();
        }
        #pragma unroll
        for (int fi = 0; fi < 4; ++fi)
        #pragma unroll
        for (int fj = 0; fj < 4; ++fj)
        #pragma unroll
        for (int j = 0; j < 4; ++j) {
            int m = m0 + wr * 64 + fi * 16 + lg * 4 + j;
            int n = n0 + wc * 64 + fj * 16 + l15;
            float v = (a0[fi][fj][j] + a1[fi][fj][j] * (1.0f / 2048.0f)) * (1.0f / 512.0f) + bias[n];
            f16 h = (f16)v;
            Ph[(size_t)m * Hn + n] = h;
            Pl[(size_t)m * Hn + n] = (f16)((v - (float)h) * 2048.0f);
        }
    } else {
        // ---- bf16 V projection ----
        short (*As)[4096] = (short(*)[4096])(smem);
        short (*Bs)[4096] = (short(*)[4096])(smem + 16384);

        auto stageB = [&](int buf, int ks) {
            const int k0 = ks << 5;
            #pragma unroll
            for (int h = 0; h < 2; ++h) {
                int s = wid + h * 4;
                int row = s * 16 + srow;
                int goff = k0 + ((sg ^ (row & 3)) << 3);
                gl_lds16(Wvt + (size_t)(n0 + row) * Hn + goff, &Bs[buf][s * 512]);
            }
        };
        auto writeA = [&](int buf, const f32x4* av) {
            #pragma unroll
            for (int rr = 0; rr < 4; ++rr) {
                int row = ar0 + rr * 32;
                s16x4 o;
                #pragma unroll
                for (int j = 0; j < 4; ++j) o[j] = bf16r(av[rr][j]);
                int off = row * 32 + (((ac0 >> 3) ^ (row & 3)) << 3) + (ac0 & 7);
                *(s16x4*)&As[buf][off] = o;
            }
        };

        f32x4 acc[4][4] = {};
        {
            f32x4 av[4];
            #pragma unroll
            for (int rr = 0; rr < 4; ++rr) av[rr] = *(const f32x4*)(aSrc[rr] + ac0);
            stageB(0, 0);
            writeA(0, av);
        }
        __syncthreads();
        #pragma unroll 1
        for (int ks = 0; ks < 16; ++ks) {
            const int cur = ks & 1, nxt = cur ^ 1;
            f32x4 av[4];
            if (ks < 15) {
                const int k1 = (ks + 1) << 5;
                #pragma unroll
                for (int rr = 0; rr < 4; ++rr) av[rr] = *(const f32x4*)(aSrc[rr] + k1 + ac0);
                stageB(nxt, ks + 1);
            }
            s16x8 fb[4];
            #pragma unroll
            for (int fj = 0; fj < 4; ++fj) {
                int row = wc * 64 + fj * 16 + l15;
                fb[fj] = *(s16x8*)&Bs[cur][row * 32 + ((lg ^ (row & 3)) << 3)];
            }
            #pragma unroll
            for (int fi = 0; fi < 4; ++fi) {
                int row = wr * 64 + fi * 16 + l15;
                s16x8 fa = *(s16x8*)&As[cur][row * 32 + ((lg ^ (row & 3)) << 3)];
                #pragma unroll
                for (int fj = 0; fj < 4; ++fj)
                    acc[fi][fj] = MFMAB16(fa, fb[fj], acc[fi][fj]);
            }
            if (ks < 15) writeA(nxt, av);
            __syncthreads();
        }
        #pragma unroll
        for (int fi = 0; fi < 4; ++fi)
        #pragma unroll
        for (int fj = 0; fj < 4; ++fj)
        #pragma unroll
        for (int j = 0; j < 4; ++j) {
            int m = m0 + wr * 64 + fi * 16 + lg * 4 + j;
            int n = n0 + wc * 64 + fj * 16 + l15;
            Vc[(size_t)m * Hn + n] = bf16r(acc[fi][fj][j] + bvec[n]);
        }
    }
}

// ---------------------------------------------------------------------------
// energy_argmax: per (128-q-tile, 128-key-chunk of compacted keys, batch).
// All staging via global_load_lds (async), double-buffered, 2-phase.
// ---------------------------------------------------------------------------
__global__ __launch_bounds__(256) void energy_argmax(
    const f16* __restrict__ Qh, const f16* __restrict__ Ql,
    const f16* __restrict__ Kh, const f16* __restrict__ Kl,
    const int* __restrict__ cnt,
    float* __restrict__ pval, int* __restrict__ pidx)
{
    __shared__ __align__(16) f16 Ah[2][4096], Al[2][4096], Bh[2][4096], Bl[2][4096];
    __shared__ float bwv[2][128];
    __shared__ int   bwi[2][128];
    const int tid = threadIdx.x, lane = tid & 63, wid = tid >> 6;
    const int wr = wid >> 1, wc = wid & 1, l15 = lane & 15, lg = lane >> 4;
    const int qt = blockIdx.x, kc = blockIdx.y, b = blockIdx.z;
    const int cn = cnt[b];
    const int kbase = kc << 7;
    if (kbase >= cn) return;
    const int m0 = b * Qn + qt * 128;
    const int kr0 = b * Kn + kbase;
    const float NEGINF = -__builtin_inff();
    const int srow = lane >> 2, sg = lane & 3;

    auto stage = [&](int buf, int ks) {
        const int k0 = ks << 5;
        #pragma unroll
        for (int h = 0; h < 2; ++h) {
            int s = wid + h * 4;
            int row = s * 16 + srow;
            int goff = k0 + ((sg ^ (row & 3)) << 3);
            size_t ga = (size_t)(m0 + row) * Hn + goff;
            size_t gb = (size_t)(kr0 + row) * Hn + goff;
            gl_lds16(Qh + ga, &Ah[buf][s * 512]);
            gl_lds16(Ql + ga, &Al[buf][s * 512]);
            gl_lds16(Kh + gb, &Bh[buf][s * 512]);
            gl_lds16(Kl + gb, &Bl[buf][s * 512]);
        }
    };

    f32x4 a0[4][4] = {}, a1[4][4] = {};
    stage(0, 0);
    __syncthreads();
    #pragma unroll 1
    for (int ks = 0; ks < 16; ++ks) {
        const int cur = ks & 1;
        if (ks < 15) stage(cur ^ 1, ks + 1);
        f16x8 fbh[4], fbl[4];
        #pragma unroll
        for (int fj = 0; fj < 4; ++fj) {
            int row = wc * 64 + fj * 16 + l15;
            int off = row * 32 + ((lg ^ (row & 3)) << 3);
            fbh[fj] = *(f16x8*)&Bh[cur][off];
            fbl[fj] = *(f16x8*)&Bl[cur][off];
        }
        #pragma unroll
        for (int fi = 0; fi < 4; ++fi) {
            int row = wr * 64 + fi * 16 + l15;
            int off = row * 32 + ((lg ^ (row & 3)) << 3);
            f16x8 fah = *(f16x8*)&Ah[cur][off];
            f16x8 fal = *(f16x8*)&Al[cur][off];
            #pragma unroll
            for (int fj = 0; fj < 4; ++fj) {
                a0[fi][fj] = MFMA16(fah, fbh[fj], a0[fi][fj]);
                a1[fi][fj] = MFMA16(fah, fbl[fj], a1[fi][fj]);
                a1[fi][fj] = MFMA16(fal, fbh[fj], a1[fi][fj]);
            }
        }
        __syncthreads();
    }
    // per-row argmax over this 128-col chunk
    #pragma unroll
    for (int fi = 0; fi < 4; ++fi) {
        #pragma unroll
        for (int j = 0; j < 4; ++j) {
            float bv = NEGINF; int bc = 0x7fffffff;
            #pragma unroll
            for (int fj = 0; fj < 4; ++fj) {
                int lc = wc * 64 + fj * 16 + l15;
                float v = a0[fi][fj][j] + a1[fi][fj][j] * (1.0f / 2048.0f);
                v = (kbase + lc < cn) ? v : NEGINF;
                if (v > bv || (v == bv && lc < bc)) { bv = v; bc = lc; }
            }
            #pragma unroll
            for (int sm = 1; sm < 16; sm <<= 1) {
                float ov = __shfl_xor(bv, sm, 64);
                int   oc = __shfl_xor(bc, sm, 64);
                if (ov > bv || (ov == bv && oc < bc)) { bv = ov; bc = oc; }
            }
            if (l15 == 0) {
                int row = wr * 64 + fi * 16 + lg * 4 + j;
                bwv[wc][row] = bv; bwi[wc][row] = bc;
            }
        }
    }
    __syncthreads();
    if (tid < 128) {
        float v0 = bwv[0][tid], v1 = bwv[1][tid];
        int   i0 = bwi[0][tid], i1 = bwi[1][tid];
        float v; int i;
        if (v0 > v1 || (v0 == v1 && i0 < i1)) { v = v0; i = i0; } else { v = v1; i = i1; }
        int m = m0 + tid;
        pval[m * 16 + kc] = v;
        pidx[m * 16 + kc] = kbase + i;
    }
}

// ---------------------------------------------------------------------------
// merge_gather: merge chunk partials -> argmax; gather Vc row -> Vg.
// ---------------------------------------------------------------------------
__global__ __launch_bounds__(256) void merge_gather(
    const float* __restrict__ pval, const int* __restrict__ pidx,
    const int* __restrict__ cnt, const int* __restrict__ cidx,
    const short* __restrict__ Vc, short* __restrict__ Vg, int* __restrict__ idxArr)
{
    int wid = threadIdx.x >> 6, lane = threadIdx.x & 63;
    int m = blockIdx.x * 4 + wid;
    int b = m >> 11;
    int nc = (cnt[b] + 127) >> 7;
    float bv = -__builtin_inff(); int bi = 0x7fffffff;
    for (int c = 0; c < nc; ++c) {
        float v = pval[m * 16 + c]; int i = pidx[m * 16 + c];
        if (v > bv || (v == bv && i < bi)) { bv = v; bi = i; }
    }
    if (lane == 0) idxArr[m] = cidx[b * Kn + bi];
    size_t src = ((size_t)(b * Kn + bi)) * Hn + lane * 8;
    size_t dst = (size_t)m * Hn + lane * 8;
    *(s16x8*)(Vg + dst) = *(const s16x8*)(Vc + src);
}

// ---------------------------------------------------------------------------
// gemm_o: res = Vg @ Wot^T + bo (f32 out), dbuf + async staging both operands.
// ---------------------------------------------------------------------------
__global__ __launch_bounds__(256) void gemm_o(
    const short* __restrict__ A, const short* __restrict__ Bt,
    const float* __restrict__ bias, float* __restrict__ Out)
{
    __shared__ __align__(16) short As[2][4096], Bs[2][4096];
    const int tid = threadIdx.x, lane = tid & 63, wid = tid >> 6;
    const int wr = wid >> 1, wc = wid & 1, l15 = lane & 15, lg = lane >> 4;
    const int m0 = blockIdx.x * 128, n0 = blockIdx.y * 128;
    const int srow = lane >> 2, sg = lane & 3;
    f32x4 acc[4][4] = {};

    auto stage = [&](int buf, int ks) {
        const int k0 = ks << 5;
        #pragma unroll
        for (int h = 0; h < 2; ++h) {
            int s = wid + h * 4;
            int row = s * 16 + srow;
            int goff = k0 + ((sg ^ (row & 3)) << 3);
            gl_lds16(A  + (size_t)(m0 + row) * Hn + goff, &As[buf][s * 512]);
            gl_lds16(Bt + (size_t)(n0 + row) * Hn + goff, &Bs[buf][s * 512]);
        }
    };

    stage(0, 0);
    __syncthreads();
    #pragma unroll 1
    for (int ks = 0; ks < 16; ++ks) {
        const int cur = ks & 1;
        if (ks < 15) stage(cur ^ 1, ks + 1);
        s16x8 fb[4];
        #pragma unroll
        for (int fj = 0; fj < 4; ++fj) {
            int row = wc * 64 + fj * 16 + l15;
            fb[fj] = *(s16x8*)&Bs[cur][row * 32 + ((lg ^ (row & 3)) << 3)];
        }
        #pragma unroll
        for (int fi = 0; fi < 4; ++fi) {
            int row = wr * 64 + fi * 16 + l15;
            s16x8 fa = *(s16x8*)&As[cur][row * 32 + ((lg ^ (row & 3)) << 3)];
            #pragma unroll
            for (int fj = 0; fj < 4; ++fj)
                acc[fi][fj] = MFMAB16(fa, fb[fj], acc[fi][fj]);
        }
        __syncthreads();
    }
    #pragma unroll
    for (int fi = 0; fi < 4; ++fi)
    #pragma unroll
    for (int fj = 0; fj < 4; ++fj)
    #pragma unroll
    for (int j = 0; j < 4; ++j) {
        int m = m0 + wr * 64 + fi * 16 + lg * 4 + j;
        int n = n0 + wc * 64 + fj * 16 + l15;
        Out[(size_t)m * Hn + n] = acc[fi][fj][j] + bias[n];
    }
}

// ---------------------------------------------------------------------------
// score_fill: one-hot rows (writes ENTIRE score region, erasing scratch).
// ---------------------------------------------------------------------------
__global__ __launch_bounds__(256) void score_fill(
    const int* __restrict__ idxArr, float* __restrict__ score)
{
    int m = blockIdx.x;
    int c = idxArr[m];
    float* row = score + (size_t)m * Kn;
    int t = threadIdx.x;
    #pragma unroll
    for (int i = 0; i < 2; ++i) {
        int v = t + i * 256;
        f32x4 val = {0.f, 0.f, 0.f, 0.f};
        if ((c >> 2) == v) val[c & 3] = 1.0f;
        *(f32x4*)(row + v * 4) = val;
    }
}

// ---------------------------------------------------------------------------
extern "C" void kernel_launch(void* const* d_in, const int* in_sizes, int n_in,
                              void* d_out, int out_size, void* d_ws, size_t ws_size,
                              hipStream_t stream)
{
    const float* query = (const float*)d_in[0];
    const float* key_  = (const float*)d_in[1];
    const float* value = (const float*)d_in[2];
    const int*   mask  = (const int*)d_in[3];
    const float* Wq = (const float*)d_in[4];
    const float* bq = (const float*)d_in[5];
    const float* Wk = (const float*)d_in[6];
    const float* bk = (const float*)d_in[7];
    const float* Wv = (const float*)d_in[8];
    const float* bv = (const float*)d_in[9];
    const float* Wo = (const float*)d_in[10];
    const float* bo = (const float*)d_in[11];

    float* res = (float*)d_out;                       // (B,Q,H) f32
    float* scoreBase = res + (size_t)Mn * Hn;         // (B,Q,K) f32, 134 MB
    char* sc = (char*)scoreBase;                      // scratch inside score region
    const size_t MB16 = (size_t)Mn * Hn * 2;          // 16 MiB
    f16*   Qp_h = (f16*)(sc + 0 * MB16);
    f16*   Qp_l = (f16*)(sc + 1 * MB16);
    f16*   Kc_h = (f16*)(sc + 2 * MB16);
    f16*   Kc_l = (f16*)(sc + 3 * MB16);
    short* Vc   = (short*)(sc + 4 * MB16);
    char*  wb   = sc + 5 * MB16;
    f16*   Wqth = (f16*)(wb + 0 * 524288);
    f16*   Wqtl = (f16*)(wb + 1 * 524288);
    f16*   Wkth = (f16*)(wb + 2 * 524288);
    f16*   Wktl = (f16*)(wb + 3 * 524288);
    short* Wvt  = (short*)(wb + 4 * 524288);
    short* Wot  = (short*)(wb + 5 * 524288);
    int*   cidx = (int*)(wb + 6 * 524288);            // 64 KB
    float* pval = (float*)(wb + 6 * 524288 + 65536);  // Mn*16 f32 = 1 MB
    int*   pidx = (int*)(wb + 6 * 524288 + 65536 + 1048576);
    short* Vg   = (short*)(sc + 0 * MB16);            // reuse Qp_h after energy

    int*   idxArr = (int*)d_ws;                       // Mn ints
    int*   cnt    = (int*)d_ws + Mn;                  // 8 ints

    compact_mask<<<Bn, 256, 0, stream>>>(mask, cidx, cnt);
    prep_w<<<1024, 256, 0, stream>>>(Wq, Wk, Wv, Wo, Wqth, Wqtl, Wkth, Wktl, Wvt, Wot);

    proj_fused<<<dim3(Mn / 128, Hn / 128, 3), 256, 0, stream>>>(
        query, key_, value, Wqth, Wqtl, Wkth, Wktl, Wvt,
        bq, bk, bv, Qp_h, Qp_l, Kc_h, Kc_l, Vc, cidx, cnt);

    energy_argmax<<<dim3(Qn / 128, 16, Bn), 256, 0, stream>>>(
        Qp_h, Qp_l, Kc_h, Kc_l, cnt, pval, pidx);

    merge_gather<<<Mn / 4, 256, 0, stream>>>(pval, pidx, cnt, cidx, Vc, Vg, idxArr);

    gemm_o<<<dim3(Mn / 128, Hn / 128), 256, 0, stream>>>(Vg, Wot, bo, res);

    score_fill<<<Mn, 256, 0, stream>>>(idxArr, scoreBase);
}

// Round 4
// 304.059 us; speedup vs baseline: 1.4712x; 1.0221x over previous
//
#include <hip/hip_runtime.h>

typedef _Float16 f16;
typedef f16 f16x8 __attribute__((ext_vector_type(8)));
typedef f16 f16x4 __attribute__((ext_vector_type(4)));
typedef short s16x8 __attribute__((ext_vector_type(8)));
typedef short s16x4 __attribute__((ext_vector_type(4)));
typedef float f32x4 __attribute__((ext_vector_type(4)));

#define MFMA16(a,b,c)  __builtin_amdgcn_mfma_f32_16x16x32_f16(a,b,c,0,0,0)
#define MFMAB16(a,b,c) __builtin_amdgcn_mfma_f32_16x16x32_bf16(a,b,c,0,0,0)

static constexpr int Bn = 8, Qn = 2048, Kn = 2048, Hn = 512;
static constexpr int Mn = Bn * Qn;           // 16384 flat rows

typedef __attribute__((address_space(1))) const unsigned int as1_uint;
typedef __attribute__((address_space(3))) unsigned int as3_uint;

__device__ __forceinline__ void gl_lds16(const void* g, void* l) {
    __builtin_amdgcn_global_load_lds((as1_uint*)g, (as3_uint*)l, 16, 0, 0);
}

__device__ __forceinline__ short bf16r(float x) {
    unsigned u = __builtin_bit_cast(unsigned, x);
    u += 0x7fffu + ((u >> 16) & 1u);
    return (short)(u >> 16);
}

// swizzle granule: 2-way (free) bank aliasing for ds_read_b128 column reads
__device__ __forceinline__ int swz(int row) { return (row >> 1) & 3; }

// ---------------------------------------------------------------------------
// compact_mask: per batch, order-preserving list of unmasked key indices.
// ---------------------------------------------------------------------------
__global__ __launch_bounds__(256) void compact_mask(
    const int* __restrict__ mask, int* __restrict__ cidx, int* __restrict__ cnt)
{
    __shared__ int sums[256];
    int b = blockIdx.x, t = threadIdx.x;
    int base = b * Kn + t * 8;
    int mv[8]; int s = 0;
    #pragma unroll
    for (int i = 0; i < 8; ++i) { mv[i] = (mask[base + i] == 0); s += mv[i]; }
    sums[t] = s;
    __syncthreads();
    for (int off = 1; off < 256; off <<= 1) {
        int v = (t >= off) ? sums[t - off] : 0;
        __syncthreads();
        sums[t] += v;
        __syncthreads();
    }
    int pos = (t > 0 ? sums[t - 1] : 0);
    #pragma unroll
    for (int i = 0; i < 8; ++i)
        if (mv[i]) cidx[b * Kn + pos++] = t * 8 + i;
    if (t == 255) {
        int total = sums[255];
        if (total == 0) { cidx[b * Kn] = 0; total = 1; }
        cnt[b] = total;
    }
}

// ---------------------------------------------------------------------------
// prep_w: transposed/split weights. Wq/Wk -> fp16 hi + lo*2^11 (x512 scale);
// Wv/Wo -> bf16.
// ---------------------------------------------------------------------------
__global__ __launch_bounds__(256) void prep_w(
    const float* __restrict__ Wq, const float* __restrict__ Wk,
    const float* __restrict__ Wv, const float* __restrict__ Wo,
    f16* __restrict__ Wqth, f16* __restrict__ Wqtl,
    f16* __restrict__ Wkth, f16* __restrict__ Wktl,
    short* __restrict__ Wvt, short* __restrict__ Wot)
{
    int e = blockIdx.x * 256 + threadIdx.x;
    int k = e >> 9, n = e & 511;
    int s = k * 512 + n, d = n * 512 + k;
    float wq = Wq[s] * 512.0f;
    f16 h = (f16)wq;
    Wqth[d] = h; Wqtl[d] = (f16)((wq - (float)h) * 2048.0f);
    float wk = Wk[s] * 512.0f;
    h = (f16)wk;
    Wkth[d] = h; Wktl[d] = (f16)((wk - (float)h) * 2048.0f);
    Wvt[d] = bf16r(Wv[s]);
    Wot[d] = bf16r(Wo[s]);
}

// ---------------------------------------------------------------------------
// proj_fused: z=0 Q-proj (split out), z=1 K-proj (indirect, split out),
// z=2 V-proj (indirect, bf16 out). 128x128 tile, dbuf LDS, async B staging.
// ---------------------------------------------------------------------------
__global__ __launch_bounds__(256) void proj_fused(
    const float* __restrict__ query, const float* __restrict__ key_,
    const float* __restrict__ value,
    const f16* __restrict__ Wqth, const f16* __restrict__ Wqtl,
    const f16* __restrict__ Wkth, const f16* __restrict__ Wktl,
    const short* __restrict__ Wvt,
    const float* __restrict__ bq, const float* __restrict__ bk,
    const float* __restrict__ bvec,
    f16* __restrict__ Qp_h, f16* __restrict__ Qp_l,
    f16* __restrict__ Kc_h, f16* __restrict__ Kc_l,
    short* __restrict__ Vc,
    const int* __restrict__ cidx, const int* __restrict__ cnt)
{
    __shared__ __align__(16) char smem[65536];
    const int which = blockIdx.z;
    const int tid = threadIdx.x, lane = tid & 63, wid = tid >> 6;
    const int wr = wid >> 1, wc = wid & 1, l15 = lane & 15, lg = lane >> 4;
    const int m0 = blockIdx.x * 128, n0 = blockIdx.y * 128;
    const int b = m0 >> 11, m0l = m0 & 2047;
    const int srow = lane >> 2, sg = lane & 3;
    const int ar0 = tid >> 3, ac0 = (tid & 7) * 4;

    int cn = 0;
    if (which > 0) {
        cn = cnt[b];
        if (m0l >= cn) return;
    }
    const float* Aptr = (which == 0) ? query : (which == 1 ? key_ : value);
    const float* aSrc[4];
    #pragma unroll
    for (int rr = 0; rr < 4; ++rr) {
        int row = ar0 + rr * 32;
        size_t grow;
        if (which > 0) {
            int r = m0l + row;
            int cid = (r < cn) ? cidx[b * Kn + r] : 0;
            grow = (size_t)(b * Kn + cid);
        } else {
            grow = (size_t)(m0 + row);
        }
        aSrc[rr] = Aptr + grow * Hn;
    }

    if (which < 2) {
        f16 (*Ah)[4096] = (f16(*)[4096])(smem);
        f16 (*Al)[4096] = (f16(*)[4096])(smem + 16384);
        f16 (*Bh)[4096] = (f16(*)[4096])(smem + 32768);
        f16 (*Bl)[4096] = (f16(*)[4096])(smem + 49152);
        const f16* Bth = (which == 0) ? Wqth : Wkth;
        const f16* Btl = (which == 0) ? Wqtl : Wktl;
        const float* bias = (which == 0) ? bq : bk;
        f16* Ph = (which == 0) ? Qp_h : Kc_h;
        f16* Pl = (which == 0) ? Qp_l : Kc_l;

        auto stageB = [&](int buf, int ks) {
            const int k0 = ks << 5;
            #pragma unroll
            for (int h = 0; h < 2; ++h) {
                int s = wid + h * 4;
                int row = s * 16 + srow;
                int goff = k0 + ((sg ^ swz(row)) << 3);
                gl_lds16(Bth + (size_t)(n0 + row) * Hn + goff, &Bh[buf][s * 512]);
                gl_lds16(Btl + (size_t)(n0 + row) * Hn + goff, &Bl[buf][s * 512]);
            }
        };
        auto writeA = [&](int buf, const f32x4* av) {
            #pragma unroll
            for (int rr = 0; rr < 4; ++rr) {
                int row = ar0 + rr * 32;
                f16x4 oh, ol;
                #pragma unroll
                for (int j = 0; j < 4; ++j) {
                    f16 hh = (f16)av[rr][j];
                    oh[j] = hh;
                    ol[j] = (f16)((av[rr][j] - (float)hh) * 2048.0f);
                }
                int off = row * 32 + (((ac0 >> 3) ^ swz(row)) << 3) + (ac0 & 7);
                *(f16x4*)&Ah[buf][off] = oh;
                *(f16x4*)&Al[buf][off] = ol;
            }
        };

        f32x4 a0[4][4] = {}, a1[4][4] = {};
        {
            f32x4 av[4];
            #pragma unroll
            for (int rr = 0; rr < 4; ++rr) av[rr] = *(const f32x4*)(aSrc[rr] + ac0);
            stageB(0, 0);
            writeA(0, av);
        }
        __syncthreads();
        #pragma unroll 1
        for (int ks = 0; ks < 16; ++ks) {
            const int cur = ks & 1, nxt = cur ^ 1;
            f32x4 av[4];
            if (ks < 15) {
                const int k1 = (ks + 1) << 5;
                #pragma unroll
                for (int rr = 0; rr < 4; ++rr) av[rr] = *(const f32x4*)(aSrc[rr] + k1 + ac0);
                stageB(nxt, ks + 1);
            }
            f16x8 fbh[4], fbl[4];
            #pragma unroll
            for (int fj = 0; fj < 4; ++fj) {
                int row = wc * 64 + fj * 16 + l15;
                int off = row * 32 + ((lg ^ swz(row)) << 3);
                fbh[fj] = *(f16x8*)&Bh[cur][off];
                fbl[fj] = *(f16x8*)&Bl[cur][off];
            }
            #pragma unroll
            for (int fi = 0; fi < 4; ++fi) {
                int row = wr * 64 + fi * 16 + l15;
                int off = row * 32 + ((lg ^ swz(row)) << 3);
                f16x8 fah = *(f16x8*)&Ah[cur][off];
                f16x8 fal = *(f16x8*)&Al[cur][off];
                #pragma unroll
                for (int fj = 0; fj < 4; ++fj) {
                    a0[fi][fj] = MFMA16(fah, fbh[fj], a0[fi][fj]);
                    a1[fi][fj] = MFMA16(fah, fbl[fj], a1[fi][fj]);
                    a1[fi][fj] = MFMA16(fal, fbh[fj], a1[fi][fj]);
                }
            }
            if (ks < 15) writeA(nxt, av);
            __syncthreads();
        }
        #pragma unroll
        for (int fi = 0; fi < 4; ++fi)
        #pragma unroll
        for (int fj = 0; fj < 4; ++fj)
        #pragma unroll
        for (int j = 0; j < 4; ++j) {
            int m = m0 + wr * 64 + fi * 16 + lg * 4 + j;
            int n = n0 + wc * 64 + fj * 16 + l15;
            float v = (a0[fi][fj][j] + a1[fi][fj][j] * (1.0f / 2048.0f)) * (1.0f / 512.0f) + bias[n];
            f16 h = (f16)v;
            Ph[(size_t)m * Hn + n] = h;
            Pl[(size_t)m * Hn + n] = (f16)((v - (float)h) * 2048.0f);
        }
    } else {
        short (*As)[4096] = (short(*)[4096])(smem);
        short (*Bs)[4096] = (short(*)[4096])(smem + 16384);

        auto stageB = [&](int buf, int ks) {
            const int k0 = ks << 5;
            #pragma unroll
            for (int h = 0; h < 2; ++h) {
                int s = wid + h * 4;
                int row = s * 16 + srow;
                int goff = k0 + ((sg ^ swz(row)) << 3);
                gl_lds16(Wvt + (size_t)(n0 + row) * Hn + goff, &Bs[buf][s * 512]);
            }
        };
        auto writeA = [&](int buf, const f32x4* av) {
            #pragma unroll
            for (int rr = 0; rr < 4; ++rr) {
                int row = ar0 + rr * 32;
                s16x4 o;
                #pragma unroll
                for (int j = 0; j < 4; ++j) o[j] = bf16r(av[rr][j]);
                int off = row * 32 + (((ac0 >> 3) ^ swz(row)) << 3) + (ac0 & 7);
                *(s16x4*)&As[buf][off] = o;
            }
        };

        f32x4 acc[4][4] = {};
        {
            f32x4 av[4];
            #pragma unroll
            for (int rr = 0; rr < 4; ++rr) av[rr] = *(const f32x4*)(aSrc[rr] + ac0);
            stageB(0, 0);
            writeA(0, av);
        }
        __syncthreads();
        #pragma unroll 1
        for (int ks = 0; ks < 16; ++ks) {
            const int cur = ks & 1, nxt = cur ^ 1;
            f32x4 av[4];
            if (ks < 15) {
                const int k1 = (ks + 1) << 5;
                #pragma unroll
                for (int rr = 0; rr < 4; ++rr) av[rr] = *(const f32x4*)(aSrc[rr] + k1 + ac0);
                stageB(nxt, ks + 1);
            }
            s16x8 fb[4];
            #pragma unroll
            for (int fj = 0; fj < 4; ++fj) {
                int row = wc * 64 + fj * 16 + l15;
                fb[fj] = *(s16x8*)&Bs[cur][row * 32 + ((lg ^ swz(row)) << 3)];
            }
            #pragma unroll
            for (int fi = 0; fi < 4; ++fi) {
                int row = wr * 64 + fi * 16 + l15;
                s16x8 fa = *(s16x8*)&As[cur][row * 32 + ((lg ^ swz(row)) << 3)];
                #pragma unroll
                for (int fj = 0; fj < 4; ++fj)
                    acc[fi][fj] = MFMAB16(fa, fb[fj], acc[fi][fj]);
            }
            if (ks < 15) writeA(nxt, av);
            __syncthreads();
        }
        #pragma unroll
        for (int fi = 0; fi < 4; ++fi)
        #pragma unroll
        for (int fj = 0; fj < 4; ++fj)
        #pragma unroll
        for (int j = 0; j < 4; ++j) {
            int m = m0 + wr * 64 + fi * 16 + lg * 4 + j;
            int n = n0 + wc * 64 + fj * 16 + l15;
            Vc[(size_t)m * Hn + n] = bf16r(acc[fi][fj][j] + bvec[n]);
        }
    }
}

// ---------------------------------------------------------------------------
// energy_argmax: per (128-q-tile, 128-key-chunk of compacted keys, batch).
// XCD-locality remap: batch = id&7 (one batch per XCD, 6 MB working set),
// 4qt x 4kc supertile order (2 MB hot set per supertile).
// ---------------------------------------------------------------------------
__global__ __launch_bounds__(256) void energy_argmax(
    const f16* __restrict__ Qh, const f16* __restrict__ Ql,
    const f16* __restrict__ Kh, const f16* __restrict__ Kl,
    const int* __restrict__ cnt,
    float* __restrict__ pval, int* __restrict__ pidx)
{
    __shared__ __align__(16) f16 Ah[2][4096], Al[2][4096], Bh[2][4096], Bl[2][4096];
    __shared__ float bwv[2][128];
    __shared__ int   bwi[2][128];
    const int tid = threadIdx.x, lane = tid & 63, wid = tid >> 6;
    const int wr = wid >> 1, wc = wid & 1, l15 = lane & 15, lg = lane >> 4;
    // bijective XCD-locality remap: id -> (b = id&7, qt, kc)
    const int id = blockIdx.x + 16 * (blockIdx.y + 16 * blockIdx.z);
    const int b  = id & 7;
    const int c  = id >> 3;                // [0,256): 16 supertiles of 16
    const int j4 = c & 15;
    const int qt = ((c >> 4) & 3) * 4 + (j4 & 3);
    const int kc = (c >> 6) * 4 + (j4 >> 2);
    const int cn = cnt[b];
    const int kbase = kc << 7;
    if (kbase >= cn) return;
    const int m0 = b * Qn + qt * 128;
    const int kr0 = b * Kn + kbase;
    const float NEGINF = -__builtin_inff();
    const int srow = lane >> 2, sg = lane & 3;

    auto stage = [&](int buf, int ks) {
        const int k0 = ks << 5;
        #pragma unroll
        for (int h = 0; h < 2; ++h) {
            int s = wid + h * 4;
            int row = s * 16 + srow;
            int goff = k0 + ((sg ^ swz(row)) << 3);
            size_t ga = (size_t)(m0 + row) * Hn + goff;
            size_t gb = (size_t)(kr0 + row) * Hn + goff;
            gl_lds16(Qh + ga, &Ah[buf][s * 512]);
            gl_lds16(Ql + ga, &Al[buf][s * 512]);
            gl_lds16(Kh + gb, &Bh[buf][s * 512]);
            gl_lds16(Kl + gb, &Bl[buf][s * 512]);
        }
    };

    f32x4 a0[4][4] = {}, a1[4][4] = {};
    stage(0, 0);
    __syncthreads();
    #pragma unroll 1
    for (int ks = 0; ks < 16; ++ks) {
        const int cur = ks & 1;
        if (ks < 15) stage(cur ^ 1, ks + 1);
        f16x8 fbh[4], fbl[4];
        #pragma unroll
        for (int fj = 0; fj < 4; ++fj) {
            int row = wc * 64 + fj * 16 + l15;
            int off = row * 32 + ((lg ^ swz(row)) << 3);
            fbh[fj] = *(f16x8*)&Bh[cur][off];
            fbl[fj] = *(f16x8*)&Bl[cur][off];
        }
        #pragma unroll
        for (int fi = 0; fi < 4; ++fi) {
            int row = wr * 64 + fi * 16 + l15;
            int off = row * 32 + ((lg ^ swz(row)) << 3);
            f16x8 fah = *(f16x8*)&Ah[cur][off];
            f16x8 fal = *(f16x8*)&Al[cur][off];
            #pragma unroll
            for (int fj = 0; fj < 4; ++fj) {
                a0[fi][fj] = MFMA16(fah, fbh[fj], a0[fi][fj]);
                a1[fi][fj] = MFMA16(fah, fbl[fj], a1[fi][fj]);
                a1[fi][fj] = MFMA16(fal, fbh[fj], a1[fi][fj]);
            }
        }
        __syncthreads();
    }
    #pragma unroll
    for (int fi = 0; fi < 4; ++fi) {
        #pragma unroll
        for (int j = 0; j < 4; ++j) {
            float bv = NEGINF; int bc = 0x7fffffff;
            #pragma unroll
            for (int fj = 0; fj < 4; ++fj) {
                int lc = wc * 64 + fj * 16 + l15;
                float v = a0[fi][fj][j] + a1[fi][fj][j] * (1.0f / 2048.0f);
                v = (kbase + lc < cn) ? v : NEGINF;
                if (v > bv || (v == bv && lc < bc)) { bv = v; bc = lc; }
            }
            #pragma unroll
            for (int sm = 1; sm < 16; sm <<= 1) {
                float ov = __shfl_xor(bv, sm, 64);
                int   oc = __shfl_xor(bc, sm, 64);
                if (ov > bv || (ov == bv && oc < bc)) { bv = ov; bc = oc; }
            }
            if (l15 == 0) {
                int row = wr * 64 + fi * 16 + lg * 4 + j;
                bwv[wc][row] = bv; bwi[wc][row] = bc;
            }
        }
    }
    __syncthreads();
    if (tid < 128) {
        float v0 = bwv[0][tid], v1 = bwv[1][tid];
        int   i0 = bwi[0][tid], i1 = bwi[1][tid];
        float v; int i;
        if (v0 > v1 || (v0 == v1 && i0 < i1)) { v = v0; i = i0; } else { v = v1; i = i1; }
        int m = m0 + tid;
        pval[m * 16 + kc] = v;
        pidx[m * 16 + kc] = kbase + i;
    }
}

// ---------------------------------------------------------------------------
// merge_gather: merge chunk partials -> argmax; gather Vc row -> Vg.
// ---------------------------------------------------------------------------
__global__ __launch_bounds__(256) void merge_gather(
    const float* __restrict__ pval, const int* __restrict__ pidx,
    const int* __restrict__ cnt, const int* __restrict__ cidx,
    const short* __restrict__ Vc, short* __restrict__ Vg, int* __restrict__ idxArr)
{
    int wid = threadIdx.x >> 6, lane = threadIdx.x & 63;
    int m = blockIdx.x * 4 + wid;
    int b = m >> 11;
    int nc = (cnt[b] + 127) >> 7;
    float bv = -__builtin_inff(); int bi = 0x7fffffff;
    for (int c = 0; c < nc; ++c) {
        float v = pval[m * 16 + c]; int i = pidx[m * 16 + c];
        if (v > bv || (v == bv && i < bi)) { bv = v; bi = i; }
    }
    if (lane == 0) idxArr[m] = cidx[b * Kn + bi];
    size_t src = ((size_t)(b * Kn + bi)) * Hn + lane * 8;
    size_t dst = (size_t)m * Hn + lane * 8;
    *(s16x8*)(Vg + dst) = *(const s16x8*)(Vc + src);
}

// ---------------------------------------------------------------------------
// gemm_o: res = Vg @ Wot^T + bo (f32 out), dbuf + async staging both operands.
// ---------------------------------------------------------------------------
__global__ __launch_bounds__(256) void gemm_o(
    const short* __restrict__ A, const short* __restrict__ Bt,
    const float* __restrict__ bias, float* __restrict__ Out)
{
    __shared__ __align__(16) short As[2][4096], Bs[2][4096];
    const int tid = threadIdx.x, lane = tid & 63, wid = tid >> 6;
    const int wr = wid >> 1, wc = wid & 1, l15 = lane & 15, lg = lane >> 4;
    const int m0 = blockIdx.x * 128, n0 = blockIdx.y * 128;
    const int srow = lane >> 2, sg = lane & 3;
    f32x4 acc[4][4] = {};

    auto stage = [&](int buf, int ks) {
        const int k0 = ks << 5;
        #pragma unroll
        for (int h = 0; h < 2; ++h) {
            int s = wid + h * 4;
            int row = s * 16 + srow;
            int goff = k0 + ((sg ^ swz(row)) << 3);
            gl_lds16(A  + (size_t)(m0 + row) * Hn + goff, &As[buf][s * 512]);
            gl_lds16(Bt + (size_t)(n0 + row) * Hn + goff, &Bs[buf][s * 512]);
        }
    };

    stage(0, 0);
    __syncthreads();
    #pragma unroll 1
    for (int ks = 0; ks < 16; ++ks) {
        const int cur = ks & 1;
        if (ks < 15) stage(cur ^ 1, ks + 1);
        s16x8 fb[4];
        #pragma unroll
        for (int fj = 0; fj < 4; ++fj) {
            int row = wc * 64 + fj * 16 + l15;
            fb[fj] = *(s16x8*)&Bs[cur][row * 32 + ((lg ^ swz(row)) << 3)];
        }
        #pragma unroll
        for (int fi = 0; fi < 4; ++fi) {
            int row = wr * 64 + fi * 16 + l15;
            s16x8 fa = *(s16x8*)&As[cur][row * 32 + ((lg ^ swz(row)) << 3)];
            #pragma unroll
            for (int fj = 0; fj < 4; ++fj)
                acc[fi][fj] = MFMAB16(fa, fb[fj], acc[fi][fj]);
        }
        __syncthreads();
    }
    #pragma unroll
    for (int fi = 0; fi < 4; ++fi)
    #pragma unroll
    for (int fj = 0; fj < 4; ++fj)
    #pragma unroll
    for (int j = 0; j < 4; ++j) {
        int m = m0 + wr * 64 + fi * 16 + lg * 4 + j;
        int n = n0 + wc * 64 + fj * 16 + l15;
        Out[(size_t)m * Hn + n] = acc[fi][fj][j] + bias[n];
    }
}

// ---------------------------------------------------------------------------
// score_fill: one-hot rows (writes ENTIRE score region, erasing scratch).
// ---------------------------------------------------------------------------
__global__ __launch_bounds__(256) void score_fill(
    const int* __restrict__ idxArr, float* __restrict__ score)
{
    int m = blockIdx.x;
    int c = idxArr[m];
    float* row = score + (size_t)m * Kn;
    int t = threadIdx.x;
    #pragma unroll
    for (int i = 0; i < 2; ++i) {
        int v = t + i * 256;
        f32x4 val = {0.f, 0.f, 0.f, 0.f};
        if ((c >> 2) == v) val[c & 3] = 1.0f;
        *(f32x4*)(row + v * 4) = val;
    }
}

// ---------------------------------------------------------------------------
extern "C" void kernel_launch(void* const* d_in, const int* in_sizes, int n_in,
                              void* d_out, int out_size, void* d_ws, size_t ws_size,
                              hipStream_t stream)
{
    const float* query = (const float*)d_in[0];
    const float* key_  = (const float*)d_in[1];
    const float* value = (const float*)d_in[2];
    const int*   mask  = (const int*)d_in[3];
    const float* Wq = (const float*)d_in[4];
    const float* bq = (const float*)d_in[5];
    const float* Wk = (const float*)d_in[6];
    const float* bk = (const float*)d_in[7];
    const float* Wv = (const float*)d_in[8];
    const float* bv = (const float*)d_in[9];
    const float* Wo = (const float*)d_in[10];
    const float* bo = (const float*)d_in[11];

    float* res = (float*)d_out;                       // (B,Q,H) f32
    float* scoreBase = res + (size_t)Mn * Hn;         // (B,Q,K) f32, 134 MB
    char* sc = (char*)scoreBase;                      // scratch inside score region
    const size_t MB16 = (size_t)Mn * Hn * 2;          // 16 MiB
    f16*   Qp_h = (f16*)(sc + 0 * MB16);
    f16*   Qp_l = (f16*)(sc + 1 * MB16);
    f16*   Kc_h = (f16*)(sc + 2 * MB16);
    f16*   Kc_l = (f16*)(sc + 3 * MB16);
    short* Vc   = (short*)(sc + 4 * MB16);
    char*  wb   = sc + 5 * MB16;
    f16*   Wqth = (f16*)(wb + 0 * 524288);
    f16*   Wqtl = (f16*)(wb + 1 * 524288);
    f16*   Wkth = (f16*)(wb + 2 * 524288);
    f16*   Wktl = (f16*)(wb + 3 * 524288);
    short* Wvt  = (short*)(wb + 4 * 524288);
    short* Wot  = (short*)(wb + 5 * 524288);
    int*   cidx = (int*)(wb + 6 * 524288);            // 64 KB
    float* pval = (float*)(wb + 6 * 524288 + 65536);  // Mn*16 f32 = 1 MB
    int*   pidx = (int*)(wb + 6 * 524288 + 65536 + 1048576);
    short* Vg   = (short*)(sc + 0 * MB16);            // reuse Qp_h after energy

    int*   idxArr = (int*)d_ws;                       // Mn ints
    int*   cnt    = (int*)d_ws + Mn;                  // 8 ints

    compact_mask<<<Bn, 256, 0, stream>>>(mask, cidx, cnt);
    prep_w<<<1024, 256, 0, stream>>>(Wq, Wk, Wv, Wo, Wqth, Wqtl, Wkth, Wktl, Wvt, Wot);

    proj_fused<<<dim3(Mn / 128, Hn / 128, 3), 256, 0, stream>>>(
        query, key_, value, Wqth, Wqtl, Wkth, Wktl, Wvt,
        bq, bk, bv, Qp_h, Qp_l, Kc_h, Kc_l, Vc, cidx, cnt);

    energy_argmax<<<dim3(16, 16, 8), 256, 0, stream>>>(
        Qp_h, Qp_l, Kc_h, Kc_l, cnt, pval, pidx);

    merge_gather<<<Mn / 4, 256, 0, stream>>>(pval, pidx, cnt, cidx, Vc, Vg, idxArr);

    gemm_o<<<dim3(Mn / 128, Hn / 128), 256, 0, stream>>>(Vg, Wot, bo, res);

    score_fill<<<Mn, 256, 0, stream>>>(idxArr, scoreBase);
}

// Round 5
// 238.982 us; speedup vs baseline: 1.8718x; 1.2723x over previous
//
#include <hip/hip_runtime.h>

typedef _Float16 f16;
typedef f16 f16x8 __attribute__((ext_vector_type(8)));
typedef f16 f16x4 __attribute__((ext_vector_type(4)));
typedef short s16x8 __attribute__((ext_vector_type(8)));
typedef short s16x4 __attribute__((ext_vector_type(4)));
typedef float f32x4 __attribute__((ext_vector_type(4)));

#define MFMA16(a,b,c)  __builtin_amdgcn_mfma_f32_16x16x32_f16(a,b,c,0,0,0)
#define MFMAB16(a,b,c) __builtin_amdgcn_mfma_f32_16x16x32_bf16(a,b,c,0,0,0)

static constexpr int Bn = 8, Qn = 2048, Kn = 2048, Hn = 512;
static constexpr int Mn = Bn * Qn;           // 16384 flat rows

typedef __attribute__((address_space(1))) const unsigned int as1_uint;
typedef __attribute__((address_space(3))) unsigned int as3_uint;

__device__ __forceinline__ void gl_lds16(const void* g, void* l) {
    __builtin_amdgcn_global_load_lds((as1_uint*)g, (as3_uint*)l, 16, 0, 0);
}

__device__ __forceinline__ short bf16r(float x) {
    unsigned u = __builtin_bit_cast(unsigned, x);
    u += 0x7fffu + ((u >> 16) & 1u);
    return (short)(u >> 16);
}

// swizzle granule: 2-way (free) bank aliasing for ds_read_b128 column reads
__device__ __forceinline__ int swz(int row) { return (row >> 1) & 3; }

// ---------------------------------------------------------------------------
// compact_mask: per batch, order-preserving list of unmasked key indices.
// ---------------------------------------------------------------------------
__global__ __launch_bounds__(256) void compact_mask(
    const int* __restrict__ mask, int* __restrict__ cidx, int* __restrict__ cnt)
{
    __shared__ int sums[256];
    int b = blockIdx.x, t = threadIdx.x;
    int base = b * Kn + t * 8;
    int mv[8]; int s = 0;
    #pragma unroll
    for (int i = 0; i < 8; ++i) { mv[i] = (mask[base + i] == 0); s += mv[i]; }
    sums[t] = s;
    __syncthreads();
    for (int off = 1; off < 256; off <<= 1) {
        int v = (t >= off) ? sums[t - off] : 0;
        __syncthreads();
        sums[t] += v;
        __syncthreads();
    }
    int pos = (t > 0 ? sums[t - 1] : 0);
    #pragma unroll
    for (int i = 0; i < 8; ++i)
        if (mv[i]) cidx[b * Kn + pos++] = t * 8 + i;
    if (t == 255) {
        int total = sums[255];
        if (total == 0) { cidx[b * Kn] = 0; total = 1; }
        cnt[b] = total;
    }
}

// ---------------------------------------------------------------------------
// prep_w: transposed/split weights. Wq/Wk -> fp16 hi + lo*2^11 (x512 scale);
// Wv/Wo -> bf16.
// ---------------------------------------------------------------------------
__global__ __launch_bounds__(256) void prep_w(
    const float* __restrict__ Wq, const float* __restrict__ Wk,
    const float* __restrict__ Wv, const float* __restrict__ Wo,
    f16* __restrict__ Wqth, f16* __restrict__ Wqtl,
    f16* __restrict__ Wkth, f16* __restrict__ Wktl,
    short* __restrict__ Wvt, short* __restrict__ Wot)
{
    int e = blockIdx.x * 256 + threadIdx.x;
    int k = e >> 9, n = e & 511;
    int s = k * 512 + n, d = n * 512 + k;
    float wq = Wq[s] * 512.0f;
    f16 h = (f16)wq;
    Wqth[d] = h; Wqtl[d] = (f16)((wq - (float)h) * 2048.0f);
    float wk = Wk[s] * 512.0f;
    h = (f16)wk;
    Wkth[d] = h; Wktl[d] = (f16)((wk - (float)h) * 2048.0f);
    Wvt[d] = bf16r(Wv[s]);
    Wot[d] = bf16r(Wo[s]);
}

// ---------------------------------------------------------------------------
// proj_fused: 64m x 128n tiles, 4 waves col-split (32 cols each), dbuf LDS,
// async B staging. z=0 Q (split out), z=1 K (indirect, split), z=2 V (bf16).
// ---------------------------------------------------------------------------
__global__ __launch_bounds__(256) void proj_fused(
    const float* __restrict__ query, const float* __restrict__ key_,
    const float* __restrict__ value,
    const f16* __restrict__ Wqth, const f16* __restrict__ Wqtl,
    const f16* __restrict__ Wkth, const f16* __restrict__ Wktl,
    const short* __restrict__ Wvt,
    const float* __restrict__ bq, const float* __restrict__ bk,
    const float* __restrict__ bvec,
    f16* __restrict__ Qp_h, f16* __restrict__ Qp_l,
    f16* __restrict__ Kc_h, f16* __restrict__ Kc_l,
    short* __restrict__ Vc,
    const int* __restrict__ cidx, const int* __restrict__ cnt)
{
    __shared__ __align__(16) char smem[49152];
    const int which = blockIdx.z;
    const int tid = threadIdx.x, lane = tid & 63, wid = tid >> 6;
    const int l15 = lane & 15, lg = lane >> 4;
    const int m0 = blockIdx.x * 64, n0 = blockIdx.y * 128;
    const int b = m0 >> 11, m0l = m0 & 2047;
    const int srow = lane >> 2, sg = lane & 3;
    const int ar0 = tid >> 3, ac0 = (tid & 7) * 4;

    int cn = 0;
    if (which > 0) {
        cn = cnt[b];
        if (m0l >= cn) return;
    }
    const float* Aptr = (which == 0) ? query : (which == 1 ? key_ : value);
    const float* aSrc[2];
    #pragma unroll
    for (int rr = 0; rr < 2; ++rr) {
        int row = ar0 + rr * 32;
        size_t grow;
        if (which > 0) {
            int r = m0l + row;
            int cid = (r < cn) ? cidx[b * Kn + r] : 0;
            grow = (size_t)(b * Kn + cid);
        } else {
            grow = (size_t)(m0 + row);
        }
        aSrc[rr] = Aptr + grow * Hn;
    }

    if (which < 2) {
        f16 (*Ah)[2048] = (f16(*)[2048])(smem);            // 2 x 4KB
        f16 (*Al)[2048] = (f16(*)[2048])(smem + 8192);
        f16 (*Bh)[4096] = (f16(*)[4096])(smem + 16384);    // 2 x 8KB
        f16 (*Bl)[4096] = (f16(*)[4096])(smem + 32768);
        const f16* Bth = (which == 0) ? Wqth : Wkth;
        const f16* Btl = (which == 0) ? Wqtl : Wktl;
        const float* bias = (which == 0) ? bq : bk;
        f16* Ph = (which == 0) ? Qp_h : Kc_h;
        f16* Pl = (which == 0) ? Qp_l : Kc_l;

        auto stageB = [&](int buf, int ks) {
            const int k0 = ks << 5;
            #pragma unroll
            for (int h = 0; h < 2; ++h) {
                int s = wid + h * 4;
                int row = s * 16 + srow;
                int goff = k0 + ((sg ^ swz(row)) << 3);
                gl_lds16(Bth + (size_t)(n0 + row) * Hn + goff, &Bh[buf][s * 512]);
                gl_lds16(Btl + (size_t)(n0 + row) * Hn + goff, &Bl[buf][s * 512]);
            }
        };
        auto writeA = [&](int buf, const f32x4* av) {
            #pragma unroll
            for (int rr = 0; rr < 2; ++rr) {
                int row = ar0 + rr * 32;
                f16x4 oh, ol;
                #pragma unroll
                for (int j = 0; j < 4; ++j) {
                    f16 hh = (f16)av[rr][j];
                    oh[j] = hh;
                    ol[j] = (f16)((av[rr][j] - (float)hh) * 2048.0f);
                }
                int off = row * 32 + (((ac0 >> 3) ^ swz(row)) << 3) + (ac0 & 7);
                *(f16x4*)&Ah[buf][off] = oh;
                *(f16x4*)&Al[buf][off] = ol;
            }
        };

        f32x4 a0[4][2] = {}, a1[4][2] = {};
        {
            f32x4 av[2];
            #pragma unroll
            for (int rr = 0; rr < 2; ++rr) av[rr] = *(const f32x4*)(aSrc[rr] + ac0);
            stageB(0, 0);
            writeA(0, av);
        }
        __syncthreads();
        #pragma unroll 1
        for (int ks = 0; ks < 16; ++ks) {
            const int cur = ks & 1, nxt = cur ^ 1;
            f32x4 av[2];
            if (ks < 15) {
                const int k1 = (ks + 1) << 5;
                #pragma unroll
                for (int rr = 0; rr < 2; ++rr) av[rr] = *(const f32x4*)(aSrc[rr] + k1 + ac0);
                stageB(nxt, ks + 1);
            }
            f16x8 fbh[2], fbl[2];
            #pragma unroll
            for (int fj = 0; fj < 2; ++fj) {
                int row = wid * 32 + fj * 16 + l15;
                int off = row * 32 + ((lg ^ swz(row)) << 3);
                fbh[fj] = *(f16x8*)&Bh[cur][off];
                fbl[fj] = *(f16x8*)&Bl[cur][off];
            }
            #pragma unroll
            for (int fi = 0; fi < 4; ++fi) {
                int row = fi * 16 + l15;
                int off = row * 32 + ((lg ^ swz(row)) << 3);
                f16x8 fah = *(f16x8*)&Ah[cur][off];
                f16x8 fal = *(f16x8*)&Al[cur][off];
                #pragma unroll
                for (int fj = 0; fj < 2; ++fj) {
                    a0[fi][fj] = MFMA16(fah, fbh[fj], a0[fi][fj]);
                    a1[fi][fj] = MFMA16(fah, fbl[fj], a1[fi][fj]);
                    a1[fi][fj] = MFMA16(fal, fbh[fj], a1[fi][fj]);
                }
            }
            if (ks < 15) writeA(nxt, av);
            __syncthreads();
        }
        #pragma unroll
        for (int fi = 0; fi < 4; ++fi)
        #pragma unroll
        for (int fj = 0; fj < 2; ++fj)
        #pragma unroll
        for (int j = 0; j < 4; ++j) {
            int m = m0 + fi * 16 + lg * 4 + j;
            int n = n0 + wid * 32 + fj * 16 + l15;
            float v = (a0[fi][fj][j] + a1[fi][fj][j] * (1.0f / 2048.0f)) * (1.0f / 512.0f) + bias[n];
            f16 h = (f16)v;
            Ph[(size_t)m * Hn + n] = h;
            Pl[(size_t)m * Hn + n] = (f16)((v - (float)h) * 2048.0f);
        }
    } else {
        short (*As)[2048] = (short(*)[2048])(smem);        // 2 x 4KB
        short (*Bs)[4096] = (short(*)[4096])(smem + 8192); // 2 x 8KB

        auto stageB = [&](int buf, int ks) {
            const int k0 = ks << 5;
            #pragma unroll
            for (int h = 0; h < 2; ++h) {
                int s = wid + h * 4;
                int row = s * 16 + srow;
                int goff = k0 + ((sg ^ swz(row)) << 3);
                gl_lds16(Wvt + (size_t)(n0 + row) * Hn + goff, &Bs[buf][s * 512]);
            }
        };
        auto writeA = [&](int buf, const f32x4* av) {
            #pragma unroll
            for (int rr = 0; rr < 2; ++rr) {
                int row = ar0 + rr * 32;
                s16x4 o;
                #pragma unroll
                for (int j = 0; j < 4; ++j) o[j] = bf16r(av[rr][j]);
                int off = row * 32 + (((ac0 >> 3) ^ swz(row)) << 3) + (ac0 & 7);
                *(s16x4*)&As[buf][off] = o;
            }
        };

        f32x4 acc[4][2] = {};
        {
            f32x4 av[2];
            #pragma unroll
            for (int rr = 0; rr < 2; ++rr) av[rr] = *(const f32x4*)(aSrc[rr] + ac0);
            stageB(0, 0);
            writeA(0, av);
        }
        __syncthreads();
        #pragma unroll 1
        for (int ks = 0; ks < 16; ++ks) {
            const int cur = ks & 1, nxt = cur ^ 1;
            f32x4 av[2];
            if (ks < 15) {
                const int k1 = (ks + 1) << 5;
                #pragma unroll
                for (int rr = 0; rr < 2; ++rr) av[rr] = *(const f32x4*)(aSrc[rr] + k1 + ac0);
                stageB(nxt, ks + 1);
            }
            s16x8 fb[2];
            #pragma unroll
            for (int fj = 0; fj < 2; ++fj) {
                int row = wid * 32 + fj * 16 + l15;
                fb[fj] = *(s16x8*)&Bs[cur][row * 32 + ((lg ^ swz(row)) << 3)];
            }
            #pragma unroll
            for (int fi = 0; fi < 4; ++fi) {
                int row = fi * 16 + l15;
                s16x8 fa = *(s16x8*)&As[cur][row * 32 + ((lg ^ swz(row)) << 3)];
                #pragma unroll
                for (int fj = 0; fj < 2; ++fj)
                    acc[fi][fj] = MFMAB16(fa, fb[fj], acc[fi][fj]);
            }
            if (ks < 15) writeA(nxt, av);
            __syncthreads();
        }
        #pragma unroll
        for (int fi = 0; fi < 4; ++fi)
        #pragma unroll
        for (int fj = 0; fj < 2; ++fj)
        #pragma unroll
        for (int j = 0; j < 4; ++j) {
            int m = m0 + fi * 16 + lg * 4 + j;
            int n = n0 + wid * 32 + fj * 16 + l15;
            Vc[(size_t)m * Hn + n] = bf16r(acc[fi][fj][j] + bvec[n]);
        }
    }
}

// ---------------------------------------------------------------------------
// energy_argmax: 64q x 128k tile, 4 waves col-split (32 cols each).
// LDS 50KB -> 3 blocks/CU. All staging async gl_lds16, dbuf, 2-phase.
// ---------------------------------------------------------------------------
__global__ __launch_bounds__(256) void energy_argmax(
    const f16* __restrict__ Qh, const f16* __restrict__ Ql,
    const f16* __restrict__ Kh, const f16* __restrict__ Kl,
    const int* __restrict__ cnt,
    float* __restrict__ pval, int* __restrict__ pidx)
{
    __shared__ __align__(16) f16 Ah[2][2048], Al[2][2048], Bh[2][4096], Bl[2][4096];
    __shared__ float bwv[4][64];
    __shared__ int   bwi[4][64];
    const int tid = threadIdx.x, lane = tid & 63, wid = tid >> 6;
    const int l15 = lane & 15, lg = lane >> 4;
    const int qt = blockIdx.x, kc = blockIdx.y, b = blockIdx.z;
    const int cn = cnt[b];
    const int kbase = kc << 7;
    if (kbase >= cn) return;
    const int m0 = b * Qn + qt * 64;
    const int kr0 = b * Kn + kbase;
    const float NEGINF = -__builtin_inff();
    const int srow = lane >> 2, sg = lane & 3;

    auto stage = [&](int buf, int ks) {
        const int k0 = ks << 5;
        {   // A: 4KB each (hi,lo) = 1 inst per wave per matrix
            int row = wid * 16 + srow;
            int goff = k0 + ((sg ^ swz(row)) << 3);
            size_t ga = (size_t)(m0 + row) * Hn + goff;
            gl_lds16(Qh + ga, &Ah[buf][wid * 512]);
            gl_lds16(Ql + ga, &Al[buf][wid * 512]);
        }
        #pragma unroll
        for (int h = 0; h < 2; ++h) {   // B: 8KB each = 2 insts per wave
            int s = wid + h * 4;
            int row = s * 16 + srow;
            int goff = k0 + ((sg ^ swz(row)) << 3);
            size_t gb = (size_t)(kr0 + row) * Hn + goff;
            gl_lds16(Kh + gb, &Bh[buf][s * 512]);
            gl_lds16(Kl + gb, &Bl[buf][s * 512]);
        }
    };

    f32x4 a0[4][2] = {}, a1[4][2] = {};
    stage(0, 0);
    __syncthreads();
    #pragma unroll 1
    for (int ks = 0; ks < 16; ++ks) {
        const int cur = ks & 1;
        if (ks < 15) stage(cur ^ 1, ks + 1);
        f16x8 fbh[2], fbl[2];
        #pragma unroll
        for (int fj = 0; fj < 2; ++fj) {
            int row = wid * 32 + fj * 16 + l15;
            int off = row * 32 + ((lg ^ swz(row)) << 3);
            fbh[fj] = *(f16x8*)&Bh[cur][off];
            fbl[fj] = *(f16x8*)&Bl[cur][off];
        }
        #pragma unroll
        for (int fi = 0; fi < 4; ++fi) {
            int row = fi * 16 + l15;
            int off = row * 32 + ((lg ^ swz(row)) << 3);
            f16x8 fah = *(f16x8*)&Ah[cur][off];
            f16x8 fal = *(f16x8*)&Al[cur][off];
            #pragma unroll
            for (int fj = 0; fj < 2; ++fj) {
                a0[fi][fj] = MFMA16(fah, fbh[fj], a0[fi][fj]);
                a1[fi][fj] = MFMA16(fah, fbl[fj], a1[fi][fj]);
                a1[fi][fj] = MFMA16(fal, fbh[fj], a1[fi][fj]);
            }
        }
        __syncthreads();
    }
    // per-row argmax: each wave owns a 32-col strip for all 64 rows
    #pragma unroll
    for (int fi = 0; fi < 4; ++fi) {
        #pragma unroll
        for (int j = 0; j < 4; ++j) {
            float bv = NEGINF; int bc = 0x7fffffff;
            #pragma unroll
            for (int fj = 0; fj < 2; ++fj) {
                int lc = wid * 32 + fj * 16 + l15;
                float v = a0[fi][fj][j] + a1[fi][fj][j] * (1.0f / 2048.0f);
                v = (kbase + lc < cn) ? v : NEGINF;
                if (v > bv || (v == bv && lc < bc)) { bv = v; bc = lc; }
            }
            #pragma unroll
            for (int sm = 1; sm < 16; sm <<= 1) {
                float ov = __shfl_xor(bv, sm, 64);
                int   oc = __shfl_xor(bc, sm, 64);
                if (ov > bv || (ov == bv && oc < bc)) { bv = ov; bc = oc; }
            }
            if (l15 == 0) {
                int row = fi * 16 + lg * 4 + j;
                bwv[wid][row] = bv; bwi[wid][row] = bc;
            }
        }
    }
    __syncthreads();
    if (tid < 64) {
        float bv = bwv[0][tid]; int bc = bwi[0][tid];
        #pragma unroll
        for (int s = 1; s < 4; ++s) {
            float v = bwv[s][tid]; int i = bwi[s][tid];
            if (v > bv || (v == bv && i < bc)) { bv = v; bc = i; }
        }
        int m = m0 + tid;
        pval[m * 16 + kc] = bv;
        pidx[m * 16 + kc] = kbase + bc;
    }
}

// ---------------------------------------------------------------------------
// merge_gather: merge chunk partials -> argmax; gather Vc row -> Vg.
// ---------------------------------------------------------------------------
__global__ __launch_bounds__(256) void merge_gather(
    const float* __restrict__ pval, const int* __restrict__ pidx,
    const int* __restrict__ cnt, const int* __restrict__ cidx,
    const short* __restrict__ Vc, short* __restrict__ Vg, int* __restrict__ idxArr)
{
    int wid = threadIdx.x >> 6, lane = threadIdx.x & 63;
    int m = blockIdx.x * 4 + wid;
    int b = m >> 11;
    int nc = (cnt[b] + 127) >> 7;
    float bv = -__builtin_inff(); int bi = 0x7fffffff;
    for (int c = 0; c < nc; ++c) {
        float v = pval[m * 16 + c]; int i = pidx[m * 16 + c];
        if (v > bv || (v == bv && i < bi)) { bv = v; bi = i; }
    }
    if (lane == 0) idxArr[m] = cidx[b * Kn + bi];
    size_t src = ((size_t)(b * Kn + bi)) * Hn + lane * 8;
    size_t dst = (size_t)m * Hn + lane * 8;
    *(s16x8*)(Vg + dst) = *(const s16x8*)(Vc + src);
}

// ---------------------------------------------------------------------------
// gemm_o: res = Vg @ Wot^T + bo (f32 out), dbuf + async staging both operands.
// ---------------------------------------------------------------------------
__global__ __launch_bounds__(256) void gemm_o(
    const short* __restrict__ A, const short* __restrict__ Bt,
    const float* __restrict__ bias, float* __restrict__ Out)
{
    __shared__ __align__(16) short As[2][4096], Bs[2][4096];
    const int tid = threadIdx.x, lane = tid & 63, wid = tid >> 6;
    const int wr = wid >> 1, wc = wid & 1, l15 = lane & 15, lg = lane >> 4;
    const int m0 = blockIdx.x * 128, n0 = blockIdx.y * 128;
    const int srow = lane >> 2, sg = lane & 3;
    f32x4 acc[4][4] = {};

    auto stage = [&](int buf, int ks) {
        const int k0 = ks << 5;
        #pragma unroll
        for (int h = 0; h < 2; ++h) {
            int s = wid + h * 4;
            int row = s * 16 + srow;
            int goff = k0 + ((sg ^ swz(row)) << 3);
            gl_lds16(A  + (size_t)(m0 + row) * Hn + goff, &As[buf][s * 512]);
            gl_lds16(Bt + (size_t)(n0 + row) * Hn + goff, &Bs[buf][s * 512]);
        }
    };

    stage(0, 0);
    __syncthreads();
    #pragma unroll 1
    for (int ks = 0; ks < 16; ++ks) {
        const int cur = ks & 1;
        if (ks < 15) stage(cur ^ 1, ks + 1);
        s16x8 fb[4];
        #pragma unroll
        for (int fj = 0; fj < 4; ++fj) {
            int row = wc * 64 + fj * 16 + l15;
            fb[fj] = *(s16x8*)&Bs[cur][row * 32 + ((lg ^ swz(row)) << 3)];
        }
        #pragma unroll
        for (int fi = 0; fi < 4; ++fi) {
            int row = wr * 64 + fi * 16 + l15;
            s16x8 fa = *(s16x8*)&As[cur][row * 32 + ((lg ^ swz(row)) << 3)];
            #pragma unroll
            for (int fj = 0; fj < 4; ++fj)
                acc[fi][fj] = MFMAB16(fa, fb[fj], acc[fi][fj]);
        }
        __syncthreads();
    }
    #pragma unroll
    for (int fi = 0; fi < 4; ++fi)
    #pragma unroll
    for (int fj = 0; fj < 4; ++fj)
    #pragma unroll
    for (int j = 0; j < 4; ++j) {
        int m = m0 + wr * 64 + fi * 16 + lg * 4 + j;
        int n = n0 + wc * 64 + fj * 16 + l15;
        Out[(size_t)m * Hn + n] = acc[fi][fj][j] + bias[n];
    }
}

// ---------------------------------------------------------------------------
// score_fill: one-hot rows (writes ENTIRE score region, erasing scratch).
// ---------------------------------------------------------------------------
__global__ __launch_bounds__(256) void score_fill(
    const int* __restrict__ idxArr, float* __restrict__ score)
{
    int m = blockIdx.x;
    int c = idxArr[m];
    float* row = score + (size_t)m * Kn;
    int t = threadIdx.x;
    #pragma unroll
    for (int i = 0; i < 2; ++i) {
        int v = t + i * 256;
        f32x4 val = {0.f, 0.f, 0.f, 0.f};
        if ((c >> 2) == v) val[c & 3] = 1.0f;
        *(f32x4*)(row + v * 4) = val;
    }
}

// ---------------------------------------------------------------------------
extern "C" void kernel_launch(void* const* d_in, const int* in_sizes, int n_in,
                              void* d_out, int out_size, void* d_ws, size_t ws_size,
                              hipStream_t stream)
{
    const float* query = (const float*)d_in[0];
    const float* key_  = (const float*)d_in[1];
    const float* value = (const float*)d_in[2];
    const int*   mask  = (const int*)d_in[3];
    const float* Wq = (const float*)d_in[4];
    const float* bq = (const float*)d_in[5];
    const float* Wk = (const float*)d_in[6];
    const float* bk = (const float*)d_in[7];
    const float* Wv = (const float*)d_in[8];
    const float* bv = (const float*)d_in[9];
    const float* Wo = (const float*)d_in[10];
    const float* bo = (const float*)d_in[11];

    float* res = (float*)d_out;                       // (B,Q,H) f32
    float* scoreBase = res + (size_t)Mn * Hn;         // (B,Q,K) f32, 134 MB
    char* sc = (char*)scoreBase;                      // scratch inside score region
    const size_t MB16 = (size_t)Mn * Hn * 2;          // 16 MiB
    f16*   Qp_h = (f16*)(sc + 0 * MB16);
    f16*   Qp_l = (f16*)(sc + 1 * MB16);
    f16*   Kc_h = (f16*)(sc + 2 * MB16);
    f16*   Kc_l = (f16*)(sc + 3 * MB16);
    short* Vc   = (short*)(sc + 4 * MB16);
    char*  wb   = sc + 5 * MB16;
    f16*   Wqth = (f16*)(wb + 0 * 524288);
    f16*   Wqtl = (f16*)(wb + 1 * 524288);
    f16*   Wkth = (f16*)(wb + 2 * 524288);
    f16*   Wktl = (f16*)(wb + 3 * 524288);
    short* Wvt  = (short*)(wb + 4 * 524288);
    short* Wot  = (short*)(wb + 5 * 524288);
    int*   cidx = (int*)(wb + 6 * 524288);            // 64 KB
    float* pval = (float*)(wb + 6 * 524288 + 65536);  // Mn*16 f32 = 1 MB
    int*   pidx = (int*)(wb + 6 * 524288 + 65536 + 1048576);
    short* Vg   = (short*)(sc + 0 * MB16);            // reuse Qp_h after energy

    int*   idxArr = (int*)d_ws;                       // Mn ints
    int*   cnt    = (int*)d_ws + Mn;                  // 8 ints

    compact_mask<<<Bn, 256, 0, stream>>>(mask, cidx, cnt);
    prep_w<<<1024, 256, 0, stream>>>(Wq, Wk, Wv, Wo, Wqth, Wqtl, Wkth, Wktl, Wvt, Wot);

    proj_fused<<<dim3(Mn / 64, Hn / 128, 3), 256, 0, stream>>>(
        query, key_, value, Wqth, Wqtl, Wkth, Wktl, Wvt,
        bq, bk, bv, Qp_h, Qp_l, Kc_h, Kc_l, Vc, cidx, cnt);

    energy_argmax<<<dim3(Qn / 64, 16, Bn), 256, 0, stream>>>(
        Qp_h, Qp_l, Kc_h, Kc_l, cnt, pval, pidx);

    merge_gather<<<Mn / 4, 256, 0, stream>>>(pval, pidx, cnt, cidx, Vc, Vg, idxArr);

    gemm_o<<<dim3(Mn / 128, Hn / 128), 256, 0, stream>>>(Vg, Wot, bo, res);

    score_fill<<<Mn, 256, 0, stream>>>(idxArr, scoreBase);
}